// Round 11
// baseline (294.008 us; speedup 1.0000x reference)
//
#include <hip/hip_runtime.h>
#include <hip/hip_bf16.h>

#define B_ 2
#define N_ 4096
#define M_ 12288
#define K_ 64
#define SH_ 32
#define H_ 64
#define GK_ 8
#define NC_ 200

#define SCAP 288       // sampler candidate cap (E=192)
#define KCAP 240       // knn candidate cap (E=128)
#define MG_ 0.01f      // theta-window safety margin (rad)
#define C256_ 81.48733086f   // 256/pi

static __device__ __forceinline__ unsigned f2key(float f) {
  unsigned b = __float_as_uint(f);
  return (b & 0x80000000u) ? ~b : (b | 0x80000000u);
}
static __device__ __forceinline__ float key2f(unsigned u) {
  unsigned b = (u & 0x80000000u) ? (u & 0x7fffffffu) : ~u;
  return __uint_as_float(b);
}
static __device__ __forceinline__ unsigned long long shflxor64(unsigned long long x, int m) {
  unsigned lo = (unsigned)x, hi = (unsigned)(x >> 32);
  lo = (unsigned)__shfl_xor((int)lo, m);
  hi = (unsigned)__shfl_xor((int)hi, m);
  return ((unsigned long long)hi << 32) | lo;
}
static __device__ __forceinline__ unsigned long long kpack(float s, int j) {
  return ((unsigned long long)f2key(s) << 14) | (unsigned)(16383 - j);
}
static __device__ __forceinline__ unsigned long long spack(float c, int n) {
  return ((unsigned long long)f2key(c) << 12) | (unsigned)(4095 - n);
}
static __device__ __forceinline__ int thbkt(float th) {
  int b = (int)(th * C256_);
  return b < 0 ? 0 : (b > 255 ? 255 : b);
}
static __device__ __forceinline__ float clamp1(float x) { return fminf(1.f, fmaxf(-1.f, x)); }
static __device__ __forceinline__ float rdlane(float v, int c) {
  return __uint_as_float((unsigned)__builtin_amdgcn_readlane((int)__float_as_uint(v), c));
}

// ---------------- sentinel ----------------
__global__ __launch_bounds__(256) void sentinel_vB(float* out, int n, float val) {
  int t = blockIdx.x * 256 + threadIdx.x;
  if (t < n) out[t] = val;
}

// ---------------- prep + thresholds + theta-band histograms ----------------
#define THRB_ 6144
#define PREPN_ (M_ + B_*N_ + B_*H_)
#define PREPB_ ((PREPN_ + 255)/256)

__global__ __launch_bounds__(256) void prepthr_vB(
    const float* __restrict__ xxx, const float* __restrict__ pix,
    float4* __restrict__ r_pix, float4* __restrict__ r_los, float* __restrict__ gf,
    float* __restrict__ kthr, float* __restrict__ cthr, unsigned* __restrict__ cnt)
{
  const float PI = 3.14159265358979f;
  if ((int)blockIdx.x < THRB_) {
    int gid  = blockIdx.x*4 + (threadIdx.x >> 6);
    int lane = threadIdx.x & 63;
    int tgt  = (gid >= M_) ? 1 : 0;
    int row  = gid - tgt*M_;
    float thp = pix[2*row];
    float cp = cosf(thp), sp = fmaxf(sinf(thp), 1e-6f);
    float thq = ((float)lane + 0.5f) * (PI/64.f);
    float sq = sinf(thq), cq = cosf(thq);
    float rinv = 1.0f / (sq * sp);
    float At = tgt ? (2.f*PI*PI*192.f/(float)N_) : (2.f*PI*PI*128.f/(float)M_);
    float lo = 1e-3f, hi = 3.1414f;
    for (int it = 0; it < 12; ++it) {
      float al = 0.5f*(lo + hi);
      float ca = cosf(al);
      float arg = clamp1((ca - cq*cp) * rinv);
      float ax = fabsf(arg);
      float ac = sqrtf(fmaxf(0.f, 1.f - ax)) *
                 fmaf(ax, fmaf(ax, fmaf(ax, -0.0187293f, 0.0742610f), -0.2121144f), 1.5707288f);
      ac = (arg < 0.f) ? (PI - ac) : ac;
      float S = ac;
      #pragma unroll
      for (int off = 32; off; off >>= 1) S += __shfl_xor(S, off);
      float A = 2.f * S * (PI/64.f);
      if (A < At) lo = al; else hi = al;
    }
    if (lane == 0) {
      float chv = cosf(hi);
      if (tgt) cthr[row] = chv - 1e-5f;
      else     kthr[row] = 2.f*chv - 1.00002f;
    }
  } else {
    int tid = ((int)blockIdx.x - THRB_)*256 + threadIdx.x;
    if (tid < M_) {
      float th = pix[2*tid], ph = pix[2*tid+1];
      float st = sinf(th);
      float x = st*cosf(ph), y = st*sinf(ph), z = cosf(th);
      r_pix[tid] = make_float4(x, y, z, x*x + y*y + z*z);
      atomicAdd(&cnt[thbkt(th)], 1u);
    }
    int t2 = tid - M_;
    if (t2 >= 0 && t2 < B_*N_) {
      int b = t2 >> 12, n = t2 & (N_-1);
      const float* xb = xxx + b*3*N_;
      float th = xb[n], ph = xb[N_+n], ft = xb[2*N_+n];
      float st = sinf(th);
      r_los[t2] = make_float4(st*cosf(ph), st*sinf(ph), cosf(th), ft);
      atomicAdd(&cnt[256 + b*256 + thbkt(th)], 1u);
    }
    int t3 = tid - M_ - B_*N_;
    if (t3 >= 0 && t3 < B_*H_) gf[t3] = 0.0f;
  }
}

// ---------------- scan ----------------
__global__ __launch_bounds__(256) void scan_vB(
    const unsigned* __restrict__ cnt, int* __restrict__ pstart, int* __restrict__ lstart,
    unsigned* __restrict__ pcur, unsigned* __restrict__ lcur)
{
  __shared__ unsigned buf[256];
  const int t = threadIdx.x;
  for (int arr = 0; arr < 3; ++arr) {
    unsigned v = cnt[arr*256 + t];
    buf[t] = v;
    __syncthreads();
    for (int off = 1; off < 256; off <<= 1) {
      unsigned o = (t >= off) ? buf[t - off] : 0u;
      __syncthreads();
      buf[t] += o;
      __syncthreads();
    }
    unsigned incl = buf[t], excl = incl - v;
    if (arr == 0) {
      pstart[t] = (int)excl; if (t == 255) pstart[256] = (int)incl;
      pcur[t] = excl;
    } else {
      int b = arr - 1;
      lstart[b*257 + t] = (int)excl; if (t == 255) lstart[b*257 + 256] = (int)incl;
      lcur[b*256 + t] = excl;
    }
    __syncthreads();
  }
}

// ---------------- scatter ----------------
__global__ __launch_bounds__(256) void scatter_vB(
    const float* __restrict__ xxx, const float* __restrict__ pix,
    const float4* __restrict__ r_pix, const float4* __restrict__ r_los,
    unsigned* __restrict__ pcur, unsigned* __restrict__ lcur,
    float4* __restrict__ spix, int* __restrict__ sjdx,
    float4* __restrict__ slos, int* __restrict__ sldx)
{
  int tid = blockIdx.x * 256 + threadIdx.x;
  if (tid < M_) {
    int bkt = thbkt(pix[2*tid]);
    unsigned pos = atomicAdd(&pcur[bkt], 1u);
    spix[pos] = r_pix[tid];
    sjdx[pos] = tid;
  } else {
    int t2 = tid - M_;
    if (t2 < B_*N_) {
      int b = t2 >> 12, n = t2 & (N_-1);
      int bkt = thbkt(xxx[b*3*N_ + n]);
      unsigned pos = atomicAdd(&lcur[b*256 + bkt], 1u);
      slos[b*N_ + pos] = r_los[t2];
      sldx[b*N_ + pos] = n;
    }
  }
}

// ---------------- fused sampler + knn: kind = blockIdx.x % 3 (0,1: sampler b; 2: knn) ----------------
__global__ __launch_bounds__(512) void samknn_vB(
    const float* __restrict__ pix,
    const float4* __restrict__ spix, const int* __restrict__ sjdx,
    const float4* __restrict__ slos, const int* __restrict__ sldx,
    const int* __restrict__ lstart, const int* __restrict__ pstart,
    const float4* __restrict__ r_pix, const float4* __restrict__ r_los,
    const float* __restrict__ cthr, const float* __restrict__ kthr,
    const float* __restrict__ aw1, const float* __restrict__ ab1,
    const float* __restrict__ aw2, const float* __restrict__ ab2,
    float* __restrict__ pooled, int* __restrict__ nbr)
{
  __shared__ unsigned long long smem[6272];   // 50176 B union

  const int tid = threadIdx.x, wv = tid >> 6, lane = tid & 63;
  const int kind = blockIdx.x % 3;
  const int grp  = blockIdx.x / 3;
  const unsigned long long ltm = (1ull << lane) - 1ull;

  if (kind < 2) {
    // ================= SAMPLER (batch b = kind) =================
    unsigned long long* cKey   = smem;                     // [16][SCAP]
    unsigned long long* selKey = smem + 16*SCAP;           // [16][64]
    unsigned* hist = (unsigned*)(smem + 16*SCAP + 16*64);  // [16][64]
    int* bnd = (int*)(hist + 16*64);                       // [16][16]

    const int b = kind;
    const int srow0 = grp*16 + wv*2, srow1 = srow0 + 1;
    const int r0 = wv*2, r1 = r0 + 1;
    const int m0 = sjdx[srow0], m1 = sjdx[srow1];
    const float4 p0 = spix[srow0], p1 = spix[srow1];
    const float thp0 = pix[2*m0], thp1 = pix[2*m1];
    float th0 = cthr[m0], th1 = cthr[m1];
    const float4* sl = slos + b * N_;
    const int* sx = sldx + b * N_;
    const float4* rl = r_los + b * N_;
    const int* ls = lstart + b * 257;

    // phase A: union window scan, candidates only (no hist in hot loop)
    unsigned cnt0 = 0, cnt1 = 0;
    {
      float al0 = acosf(clamp1(th0)), al1 = acosf(clamp1(th1));
      int blo = thbkt(fminf(thp0 - al0, thp1 - al1) - MG_);
      int bhi = thbkt(fmaxf(thp0 + al0, thp1 + al1) + MG_);
      int jlo = ls[blo], jhi = ls[bhi + 1];
      for (int base = jlo; base < jhi; base += 64) {
        int pos = base + lane;
        bool act = pos < jhi;
        float c0 = -2.f, c1 = -2.f; int n = 0;
        if (act) {
          float4 v = sl[pos]; n = sx[pos];
          c0 = clamp1(v.x*p0.x + v.y*p0.y + v.z*p0.z);
          c1 = clamp1(v.x*p1.x + v.y*p1.y + v.z*p1.z);
        }
        bool pr0 = c0 > th0, pr1 = c1 > th1;
        unsigned long long mk0 = __ballot(pr0);
        if (mk0) {
          unsigned off = (unsigned)__popcll(mk0 & ltm);
          if (pr0 && cnt0 + off < SCAP) cKey[r0*SCAP + cnt0 + off] = spack(c0, n);
          cnt0 += (unsigned)__popcll(mk0);
        }
        unsigned long long mk1 = __ballot(pr1);
        if (mk1) {
          unsigned off = (unsigned)__popcll(mk1 & ltm);
          if (pr1 && cnt1 + off < SCAP) cKey[r1*SCAP + cnt1 + off] = spack(c1, n);
          cnt1 += (unsigned)__popcll(mk1);
        }
      }
    }

    for (int rr = 0; rr < 2; ++rr) {
      const int r = (rr == 0) ? r0 : r1;
      const int m = (rr == 0) ? m0 : m1;
      const float4 p = (rr == 0) ? p0 : p1;
      const float thp = (rr == 0) ? thp0 : thp1;
      float th = (rr == 0) ? th0 : th1;
      unsigned cn = (rr == 0) ? cnt0 : cnt1;

      int tries = 0;
      while (cn < K_ && tries < 3) {
        th = 1.f - 1.6f*(1.f - th); ++tries;
        float al = acosf(clamp1(th));
        int blo = thbkt(thp - al - MG_), bhi = thbkt(thp + al + MG_);
        int jlo = ls[blo], jhi = ls[bhi + 1];
        cn = 0;
        for (int base = jlo; base < jhi; base += 64) {
          int pos = base + lane;
          bool act = pos < jhi;
          float c = -2.f; int n = 0;
          if (act) {
            float4 v = sl[pos]; n = sx[pos];
            c = clamp1(v.x*p.x + v.y*p.y + v.z*p.z);
          }
          bool pr = c > th;
          unsigned long long mk = __ballot(pr);
          if (mk) {
            unsigned off = (unsigned)__popcll(mk & ltm);
            if (pr && cn + off < SCAP) cKey[r*SCAP + cn + off] = spack(c, n);
            cn += (unsigned)__popcll(mk);
          }
        }
      }

      if (cn < K_ || cn > SCAP) {
        // ultimate exact: 64 rounds bounded argmax over full row
        unsigned long long prev = ~0ull;
        for (int rd = 0; rd < K_; ++rd) {
          unsigned long long best = 0ull;
          for (int i = 0; i < 64; ++i) {
            int n = lane + 64*i;
            float4 v = rl[n];
            float c = clamp1(v.x*p.x + v.y*p.y + v.z*p.z);
            unsigned long long k = spack(c, n);
            if (k < prev && k > best) best = k;
          }
          #pragma unroll
          for (int off = 1; off < 64; off <<= 1) {
            unsigned long long o = shflxor64(best, off);
            best = o > best ? o : best;
          }
          if (lane == 0) selKey[r*64 + rd] = best;
          prev = best;
        }
      } else {
        // separate hist pass over candidates (v9-proven; out of the hot loop)
        const float inv = 63.999f / (1.000001f - th);
        hist[r*64 + lane] = 0u;
        for (unsigned base = 0; base < cn; base += 64) {
          unsigned it = base + lane;
          if (it < cn) {
            float c = key2f((unsigned)(cKey[r*SCAP + it] >> 12));
            atomicAdd(&hist[r*64 + (int)((c - th) * inv)], 1u);
          }
        }
        // suffix-scan over 64 bins (1/lane)
        unsigned g = hist[r*64 + lane], s = g;
        #pragma unroll
        for (int off = 1; off < 64; off <<= 1) {
          unsigned t2 = (unsigned)__shfl_down((int)s, off);
          s += (lane + off < 64) ? t2 : 0u;
        }
        unsigned snext = s - g;
        unsigned packed = (s >= K_ && snext < K_) ? (((unsigned)(lane+1) << 16) | snext) : 0u;
        #pragma unroll
        for (int off = 32; off; off >>= 1) {
          unsigned o = (unsigned)__shfl_xor((int)packed, off);
          packed = packed > o ? packed : o;
        }
        const int t = (int)(packed >> 16) - 1;
        const unsigned chi = packed & 0xFFFFu;
        const unsigned need = K_ - chi;
        // collect winners (bin > t) + boundary (bin == t)
        unsigned hiC = 0, bdC = 0;
        for (unsigned base = 0; base < cn; base += 64) {
          unsigned it = base + lane;
          bool act = it < cn;
          unsigned long long key = act ? cKey[r*SCAP + it] : 0ull;
          int bin = -1;
          if (act) bin = (int)((key2f((unsigned)(key >> 12)) - th) * inv);
          bool pHi = act && bin > t;
          bool pBd = act && bin == t;
          unsigned long long mH = __ballot(pHi);
          unsigned offH = (unsigned)__popcll(mH & ltm);
          if (pHi && hiC + offH < K_) selKey[r*64 + hiC + offH] = key;
          hiC += (unsigned)__popcll(mH);
          unsigned long long mB = __ballot(pBd);
          unsigned offB = (unsigned)__popcll(mB & ltm);
          if (pBd && bdC + offB < 16u) bnd[r*16 + bdC + offB] = (int)it;
          bdC += (unsigned)__popcll(mB);
        }
        if (bdC <= 16u) {
          if (lane < (int)bdC) {
            unsigned long long ki = cKey[r*SCAP + bnd[r*16 + lane]];
            int rank = 0;
            for (int j = 0; j < (int)bdC; ++j) rank += (cKey[r*SCAP + bnd[r*16 + j]] > ki) ? 1 : 0;
            if ((unsigned)rank < need) selKey[r*64 + chi + rank] = ki;
          }
        } else {
          for (unsigned base = 0; base < cn; base += 64) {
            unsigned it = base + lane;
            if (it < cn) {
              unsigned long long ki = cKey[r*SCAP + it];
              int bin = (int)((key2f((unsigned)(ki >> 12)) - th) * inv);
              if (bin == t) {
                int rank = 0;
                for (unsigned j = 0; j < cn; ++j) {
                  unsigned long long kj = cKey[r*SCAP + j];
                  int bj = (int)((key2f((unsigned)(kj >> 12)) - th) * inv);
                  rank += (bj == t && kj > ki) ? 1 : 0;
                }
                if ((unsigned)rank < need) selKey[r*64 + chi + rank] = ki;
              }
            }
          }
        }
      }

      // attention MLP + softmax + weighted pool
      {
        unsigned long long key = selKey[r*64 + lane];
        int n = 4095 - (int)(key & 0xFFFull);
        float c = key2f((unsigned)(key >> 12));
        float xg = rl[n].w;
        float d  = acosf(clamp1(c));
        float acc = ab2[0];
        for (int s2 = 0; s2 < SH_; ++s2)
          acc += fmaxf(xg*aw1[s2] + d*aw1[SH_+s2] + ab1[s2], 0.f) * aw2[s2];
        float mx = acc;
        #pragma unroll
        for (int off = 32; off; off >>= 1) mx = fmaxf(mx, __shfl_xor(mx, off));
        float e = expf(acc - mx);
        float se = e, sxe = e * xg;
        #pragma unroll
        for (int off = 32; off; off >>= 1) { se += __shfl_xor(se, off); sxe += __shfl_xor(sxe, off); }
        if (lane == 0) pooled[b*M_ + m] = sxe / se;
      }
    }
  } else {
    // ================= KNN =================
    unsigned long long* cKey = smem;   // [16][KCAP]

    const int lr0 = wv*2;
    const int srow0 = grp*16 + lr0, srow1 = srow0 + 1;
    const int i0 = sjdx[srow0], i1 = sjdx[srow1];
    const float4 p0 = spix[srow0], p1 = spix[srow1];
    const float thp0 = pix[2*i0], thp1 = pix[2*i1];
    const float t0 = kthr[i0], t1 = kthr[i1];

    unsigned cnt0 = 0, cnt1 = 0;
    {
      float al0 = acosf(clamp1((t0 + 1.00002f)*0.5f));
      float al1 = acosf(clamp1((t1 + 1.00002f)*0.5f));
      int blo = thbkt(fminf(thp0 - al0, thp1 - al1) - MG_);
      int bhi = thbkt(fmaxf(thp0 + al0, thp1 + al1) + MG_);
      int jlo = pstart[blo], jhi = pstart[bhi + 1];
      for (int base = jlo; base < jhi; base += 64) {
        int pos = base + lane;
        bool act = pos < jhi;
        float s0 = -1e30f, s1 = -1e30f; int j = -1;
        if (act) {
          float4 v = spix[pos]; j = sjdx[pos];
          s0 = 2.f*(p0.x*v.x + p0.y*v.y + p0.z*v.z) - v.w;
          s1 = 2.f*(p1.x*v.x + p1.y*v.y + p1.z*v.z) - v.w;
        }
        bool pr0 = act && (j != i0) && (s0 > t0);
        bool pr1 = act && (j != i1) && (s1 > t1);
        unsigned long long mk0 = __ballot(pr0);
        if (mk0) {
          unsigned off = (unsigned)__popcll(mk0 & ltm);
          if (pr0 && cnt0 + off < KCAP) cKey[lr0*KCAP + cnt0 + off] = kpack(s0, j);
          cnt0 += (unsigned)__popcll(mk0);
        }
        unsigned long long mk1 = __ballot(pr1);
        if (mk1) {
          unsigned off = (unsigned)__popcll(mk1 & ltm);
          if (pr1 && cnt1 + off < KCAP) cKey[(lr0+1)*KCAP + cnt1 + off] = kpack(s1, j);
          cnt1 += (unsigned)__popcll(mk1);
        }
      }
    }

    for (int rr = 0; rr < 2; ++rr) {
      const int lr = lr0 + rr;
      const int i  = (rr == 0) ? i0 : i1;
      const float4 pi = (rr == 0) ? p0 : p1;
      const float thp = (rr == 0) ? thp0 : thp1;
      float th = (rr == 0) ? t0 : t1;
      unsigned cn = (rr == 0) ? cnt0 : cnt1;

      int tries = 0;
      while (cn < (unsigned)GK_ && tries < 3) {
        th = 1.6f*th - 0.6f; ++tries;
        float al = acosf(clamp1((th + 1.00002f)*0.5f));
        int blo = thbkt(thp - al - MG_), bhi = thbkt(thp + al + MG_);
        int jlo = pstart[blo], jhi = pstart[bhi + 1];
        cn = 0;
        for (int base = jlo; base < jhi; base += 64) {
          int pos = base + lane;
          bool act = pos < jhi;
          float s = -1e30f; int j = -1;
          if (act) {
            float4 v = spix[pos]; j = sjdx[pos];
            s = 2.f*(pi.x*v.x + pi.y*v.y + pi.z*v.z) - v.w;
          }
          bool pr = act && (j != i) && (s > th);
          unsigned long long mk = __ballot(pr);
          if (mk) {
            unsigned off = (unsigned)__popcll(mk & ltm);
            if (pr && cn + off < KCAP) cKey[lr*KCAP + cn + off] = kpack(s, j);
            cn += (unsigned)__popcll(mk);
          }
        }
      }

      if (cn >= (unsigned)GK_ && cn <= (unsigned)KCAP) {
        unsigned long long pk[4];
        #pragma unroll
        for (int t2 = 0; t2 < 4; ++t2) {
          int idx = lane + 64*t2;
          pk[t2] = (idx < (int)cn) ? cKey[lr*KCAP + idx] : 0ull;
        }
        for (int round = 0; round < GK_; ++round) {
          unsigned long long loc = pk[0]; int lt = 0;
          #pragma unroll
          for (int t2 = 1; t2 < 4; ++t2) if (pk[t2] > loc) { loc = pk[t2]; lt = t2; }
          unsigned long long best = loc;
          #pragma unroll
          for (int off = 1; off < 64; off <<= 1) {
            unsigned long long o = shflxor64(best, off);
            best = o > best ? o : best;
          }
          if (loc == best) {
            #pragma unroll
            for (int t2 = 0; t2 < 4; ++t2) if (t2 == lt) pk[t2] = 0ull;
          }
          if (lane == round) nbr[i*GK_ + round] = 16383 - (int)(best & 16383ull);
        }
      } else {
        unsigned long long prev = ~0ull;
        for (int rd = 0; rd < GK_; ++rd) {
          unsigned long long best = 0ull;
          for (int j = lane; j < M_; j += 64) {
            float4 v = r_pix[j];
            float s = 2.f*(pi.x*v.x + pi.y*v.y + pi.z*v.z) - v.w;
            if (j != i) {
              unsigned long long k = kpack(s, j);
              if (k < prev && k > best) best = k;
            }
          }
          #pragma unroll
          for (int off = 1; off < 64; off <<= 1) {
            unsigned long long o = shflxor64(best, off);
            best = o > best ? o : best;
          }
          if (lane == rd) nbr[i*GK_ + rd] = 16383 - (int)(best & 16383ull);
          prev = best;
        }
      }
    }
  }
}

// ---------------- GNN layer 1 fused with proj (readlane matmul) ----------------
__global__ __launch_bounds__(256) void gnn1f_vB(
    const float* __restrict__ pooled, float* __restrict__ hout, const int* __restrict__ nbr,
    const float* __restrict__ pw, const float* __restrict__ pb,
    const float* __restrict__ relw, const float* __restrict__ relb,
    const float* __restrict__ rootw)
{
  __shared__ float wrel[H_*H_], wroot[H_*H_];
  const int tid = threadIdx.x;
  #pragma unroll
  for (int q = 0; q < 16; ++q) {
    int idx = tid + 256*q;
    wrel[idx]  = relw[idx];
    wroot[idx] = rootw[idx];
  }
  __syncthreads();

  const int lane = tid & 63;
  const int wave = tid >> 6;
  const int b = blockIdx.y;
  const int m0 = blockIdx.x * 16 + wave * 4;
  const float* pldb = pooled + (size_t)b * M_;
  const float pwl = pw[lane], pbl = pb[lane], rbl = relb[lane];

  float h[4], agg[4], acc[4];
  #pragma unroll
  for (int t = 0; t < 4; ++t) {
    int m = m0 + t;
    float ps = pldb[m];
    h[t] = fmaxf(ps*pwl + pbl, 0.f);
    float a = 0.f;
    #pragma unroll
    for (int k = 0; k < GK_; ++k) {
      int nb = nbr[m*GK_ + k];
      nb = nb < 0 ? 0 : (nb >= M_ ? M_-1 : nb);
      float pn = pldb[nb];
      a += fmaxf(pn*pwl + pbl, 0.f);
    }
    agg[t] = a;
    acc[t] = rbl;
  }
  #pragma unroll
  for (int c = 0; c < H_; ++c) {
    float wr = wrel[c*H_ + lane], wo = wroot[c*H_ + lane];
    #pragma unroll
    for (int t = 0; t < 4; ++t)
      acc[t] += rdlane(agg[t], c) * wr + rdlane(h[t], c) * wo;
  }
  #pragma unroll
  for (int t = 0; t < 4; ++t)
    hout[((size_t)b*M_ + m0 + t)*H_ + lane] = fmaxf(acc[t], 0.f);
}

// ---------------- GNN layer (generic, readlane matmul) ----------------
__global__ __launch_bounds__(256) void gnn_vB(
    const float* __restrict__ hin, float* __restrict__ hout, const int* __restrict__ nbr,
    const float* __restrict__ relw, const float* __restrict__ relb,
    const float* __restrict__ rootw)
{
  __shared__ float wrel[H_*H_], wroot[H_*H_];
  const int tid = threadIdx.x;
  #pragma unroll
  for (int q = 0; q < 16; ++q) {
    int idx = tid + 256*q;
    wrel[idx]  = relw[idx];
    wroot[idx] = rootw[idx];
  }
  __syncthreads();

  const int lane = tid & 63;
  const int wave = tid >> 6;
  const int b = blockIdx.y;
  const int m0 = blockIdx.x * 16 + wave * 4;
  const float* hb = hin + (size_t)b * M_ * H_;
  const float rbl = relb[lane];

  float h[4], agg[4], acc[4];
  #pragma unroll
  for (int t = 0; t < 4; ++t) {
    int m = m0 + t;
    h[t] = hb[m*H_ + lane];
    float a = 0.f;
    #pragma unroll
    for (int k = 0; k < GK_; ++k) {
      int nb = nbr[m*GK_ + k];
      nb = nb < 0 ? 0 : (nb >= M_ ? M_-1 : nb);
      a += hb[nb*H_ + lane];
    }
    agg[t] = a;
    acc[t] = rbl;
  }
  #pragma unroll
  for (int c = 0; c < H_; ++c) {
    float wr = wrel[c*H_ + lane], wo = wroot[c*H_ + lane];
    #pragma unroll
    for (int t = 0; t < 4; ++t)
      acc[t] += rdlane(agg[t], c) * wr + rdlane(h[t], c) * wo;
  }
  #pragma unroll
  for (int t = 0; t < 4; ++t)
    hout[((size_t)b*M_ + m0 + t)*H_ + lane] = fmaxf(acc[t], 0.f);
}

// ---------------- GNN layer 3 + fused global-mean reduce ----------------
__global__ __launch_bounds__(256) void gnn3r_vB(
    const float* __restrict__ hin, float* __restrict__ gf, const int* __restrict__ nbr,
    const float* __restrict__ relw, const float* __restrict__ relb,
    const float* __restrict__ rootw)
{
  __shared__ float wrel[H_*H_], wroot[H_*H_];
  __shared__ float gacc[H_];
  const int tid = threadIdx.x;
  #pragma unroll
  for (int q = 0; q < 16; ++q) {
    int idx = tid + 256*q;
    wrel[idx]  = relw[idx];
    wroot[idx] = rootw[idx];
  }
  if (tid < H_) gacc[tid] = 0.f;
  __syncthreads();

  const int lane = tid & 63;
  const int wave = tid >> 6;
  const int b = blockIdx.y;
  const int m0 = blockIdx.x * 16 + wave * 4;
  const float* hb = hin + (size_t)b * M_ * H_;
  const float rbl = relb[lane];

  float h[4], agg[4], acc[4];
  #pragma unroll
  for (int t = 0; t < 4; ++t) {
    int m = m0 + t;
    h[t] = hb[m*H_ + lane];
    float a = 0.f;
    #pragma unroll
    for (int k = 0; k < GK_; ++k) {
      int nb = nbr[m*GK_ + k];
      nb = nb < 0 ? 0 : (nb >= M_ ? M_-1 : nb);
      a += hb[nb*H_ + lane];
    }
    agg[t] = a;
    acc[t] = rbl;
  }
  #pragma unroll
  for (int c = 0; c < H_; ++c) {
    float wr = wrel[c*H_ + lane], wo = wroot[c*H_ + lane];
    #pragma unroll
    for (int t = 0; t < 4; ++t)
      acc[t] += rdlane(agg[t], c) * wr + rdlane(h[t], c) * wo;
  }
  float ps = fmaxf(acc[0], 0.f) + fmaxf(acc[1], 0.f) + fmaxf(acc[2], 0.f) + fmaxf(acc[3], 0.f);
  atomicAdd(&gacc[lane], ps);
  __syncthreads();
  if (tid < H_) atomicAdd(&gf[b*H_ + tid], gacc[tid]);
}

// ---------------- head ----------------
__global__ __launch_bounds__(256) void head_vB(
    const float* __restrict__ gf, const float* __restrict__ w1,
    const float* __restrict__ b1, const float* __restrict__ w2,
    const float* __restrict__ b2, float* __restrict__ out)
{
  __shared__ float gfm[B_][H_], hid[B_][H_];
  const int tid = threadIdx.x;
  if (tid < B_*H_) gfm[tid >> 6][tid & 63] = gf[tid] * (1.f / (float)M_);
  __syncthreads();
  if (tid < B_*H_) {
    int b = tid >> 6, j = tid & 63;
    float acc = b1[j];
    for (int c = 0; c < H_; ++c) acc += gfm[b][c] * w1[c*H_ + j];
    hid[b][j] = fmaxf(acc, 0.f);
  }
  __syncthreads();
  for (int t = tid; t < B_*NC_; t += 256) {
    int b = t / NC_, o = t - b*NC_;
    float acc = b2[o];
    for (int j = 0; j < H_; ++j) acc += hid[b][j] * w2[j*NC_ + o];
    out[t] = acc;
  }
}

extern "C" void kernel_launch(void* const* d_in, const int* in_sizes, int n_in,
                              void* d_out, int out_size, void* d_ws, size_t ws_size,
                              hipStream_t stream)
{
  float* out = (float*)d_out;

  const size_t need = (size_t)M_*16 + (size_t)B_*N_*16 + (size_t)B_*M_*4
                    + (size_t)M_*GK_*4 + 2*(size_t)B_*M_*H_*4 + (size_t)B_*H_*4;
  bool ok_ws = ws_size >= need;
  bool ok_in = (n_in == 15) && (out_size == B_*NC_)
            && in_sizes[0] == B_*3*N_ && in_sizes[1] == M_*2
            && in_sizes[2] == 2*SH_ && in_sizes[5] == 1
            && in_sizes[8] == 3*H_*H_ && in_sizes[13] == H_*NC_;
  if (!ok_ws || !ok_in) {
    sentinel_vB<<<(out_size + 255)/256, 256, 0, stream>>>(out, out_size, ok_in ? 42.f : 43.f);
    return;
  }

  const float* xxx    = (const float*)d_in[0];
  const float* pix    = (const float*)d_in[1];
  const float* att_w1 = (const float*)d_in[2];
  const float* att_b1 = (const float*)d_in[3];
  const float* att_w2 = (const float*)d_in[4];
  const float* att_b2 = (const float*)d_in[5];
  const float* proj_w = (const float*)d_in[6];
  const float* proj_b = (const float*)d_in[7];
  const float* rel_w  = (const float*)d_in[8];
  const float* rel_b  = (const float*)d_in[9];
  const float* root_w = (const float*)d_in[10];
  const float* out_w1 = (const float*)d_in[11];
  const float* out_b1 = (const float*)d_in[12];
  const float* out_w2 = (const float*)d_in[13];
  const float* out_b2 = (const float*)d_in[14];

  char* w = (char*)d_ws;
  float4* r_pix = (float4*)w;  w += (size_t)M_ * 16;
  float4* r_los = (float4*)w;  w += (size_t)B_ * N_ * 16;
  float*  pooled = (float*)w;  w += (size_t)B_ * M_ * 4;
  int*    nbr = (int*)w;       w += (size_t)M_ * GK_ * 4;
  float*  h0 = (float*)w;      w += (size_t)B_ * M_ * H_ * 4;
  float*  h1 = (float*)w;      w += (size_t)B_ * M_ * H_ * 4;
  float*  gf = (float*)w;      w += (size_t)B_ * H_ * 4;

  // sort/threshold scratch aliases h0 (dead until gnn layer 2 writes it)
  float*  kthr = h0;                                   // M
  float*  cthr = h0 + M_;                              // M
  float4* spix = (float4*)(h0 + 2*M_);                 // M float4
  int*    sjdx = (int*)(h0 + 6*M_);                    // M
  float4* slos = (float4*)(h0 + 7*M_);                 // B*N float4
  int*    sldx = (int*)(h0 + 7*M_ + 4*B_*N_);          // B*N
  unsigned* cnt = (unsigned*)(h0 + 7*M_ + 5*B_*N_);    // 768
  int*    pstart = (int*)(cnt + 768);                  // 257
  int*    lstart = pstart + 257;                       // 2*257
  unsigned* pcur = (unsigned*)(lstart + 514);          // 256
  unsigned* lcur = pcur + 256;                         // 512

  hipMemsetAsync(cnt, 0, 768*sizeof(unsigned), stream);
  prepthr_vB<<<THRB_ + PREPB_, 256, 0, stream>>>(xxx, pix, r_pix, r_los, gf, kthr, cthr, cnt);
  scan_vB<<<1, 256, 0, stream>>>(cnt, pstart, lstart, pcur, lcur);
  scatter_vB<<<(M_ + B_*N_ + 255)/256, 256, 0, stream>>>(xxx, pix, r_pix, r_los, pcur, lcur,
                                                         spix, sjdx, slos, sldx);
  samknn_vB<<<3*(M_/16), 512, 0, stream>>>(pix, spix, sjdx, slos, sldx, lstart, pstart,
                                           r_pix, r_los, cthr, kthr,
                                           att_w1, att_b1, att_w2, att_b2, pooled, nbr);
  gnn1f_vB<<<dim3(M_/16, B_), 256, 0, stream>>>(pooled, h1, nbr, proj_w, proj_b,
                                                rel_w + 0*H_*H_, rel_b + 0*H_, root_w + 0*H_*H_);
  gnn_vB<<<dim3(M_/16, B_), 256, 0, stream>>>(h1, h0, nbr, rel_w + 1*H_*H_, rel_b + 1*H_, root_w + 1*H_*H_);
  gnn3r_vB<<<dim3(M_/16, B_), 256, 0, stream>>>(h0, gf, nbr, rel_w + 2*H_*H_, rel_b + 2*H_, root_w + 2*H_*H_);
  head_vB<<<1, 256, 0, stream>>>(gf, out_w1, out_b1, out_w2, out_b2, out);
}

// Round 12
// 287.636 us; speedup vs baseline: 1.0222x; 1.0222x over previous
//
#include <hip/hip_runtime.h>
#include <hip/hip_bf16.h>

#define B_ 2
#define N_ 4096
#define M_ 12288
#define K_ 64
#define SH_ 32
#define H_ 64
#define GK_ 8
#define NC_ 200

#define KCAP 240       // knn candidate cap (E=128)
#define BCAP2 48       // sampler boundary cap
#define MG_ 0.01f      // theta-window safety margin (rad)
#define C256_ 81.48733086f   // 256/pi

static __device__ __forceinline__ unsigned f2key(float f) {
  unsigned b = __float_as_uint(f);
  return (b & 0x80000000u) ? ~b : (b | 0x80000000u);
}
static __device__ __forceinline__ float key2f(unsigned u) {
  unsigned b = (u & 0x80000000u) ? (u & 0x7fffffffu) : ~u;
  return __uint_as_float(b);
}
static __device__ __forceinline__ unsigned long long shflxor64(unsigned long long x, int m) {
  unsigned lo = (unsigned)x, hi = (unsigned)(x >> 32);
  lo = (unsigned)__shfl_xor((int)lo, m);
  hi = (unsigned)__shfl_xor((int)hi, m);
  return ((unsigned long long)hi << 32) | lo;
}
static __device__ __forceinline__ unsigned long long kpack(float s, int j) {
  return ((unsigned long long)f2key(s) << 14) | (unsigned)(16383 - j);
}
static __device__ __forceinline__ unsigned long long spack(float c, int n) {
  return ((unsigned long long)f2key(c) << 12) | (unsigned)(4095 - n);
}
static __device__ __forceinline__ int thbkt(float th) {
  int b = (int)(th * C256_);
  return b < 0 ? 0 : (b > 255 ? 255 : b);
}
static __device__ __forceinline__ float clamp1(float x) { return fminf(1.f, fmaxf(-1.f, x)); }
static __device__ __forceinline__ float rdlane(float v, int c) {
  return __uint_as_float((unsigned)__builtin_amdgcn_readlane((int)__float_as_uint(v), c));
}

// ---------------- sentinel ----------------
__global__ __launch_bounds__(256) void sentinel_vC(float* out, int n, float val) {
  int t = blockIdx.x * 256 + threadIdx.x;
  if (t < n) out[t] = val;
}

// ---------------- prep + thresholds + theta-band histograms ----------------
#define THRB_ 6144
#define PREPN_ (M_ + B_*N_ + B_*H_)
#define PREPB_ ((PREPN_ + 255)/256)

__global__ __launch_bounds__(256) void prepthr_vC(
    const float* __restrict__ xxx, const float* __restrict__ pix,
    float4* __restrict__ r_pix, float4* __restrict__ r_los, float* __restrict__ gf,
    float* __restrict__ kthr, float* __restrict__ cthr, unsigned* __restrict__ cnt)
{
  const float PI = 3.14159265358979f;
  if ((int)blockIdx.x < THRB_) {
    int gid  = blockIdx.x*4 + (threadIdx.x >> 6);
    int lane = threadIdx.x & 63;
    int tgt  = (gid >= M_) ? 1 : 0;
    int row  = gid - tgt*M_;
    float thp = pix[2*row];
    float cp = cosf(thp), sp = fmaxf(sinf(thp), 1e-6f);
    float thq = ((float)lane + 0.5f) * (PI/64.f);
    float sq = sinf(thq), cq = cosf(thq);
    float rinv = 1.0f / (sq * sp);
    float At = tgt ? (2.f*PI*PI*192.f/(float)N_) : (2.f*PI*PI*128.f/(float)M_);
    float lo = 1e-3f, hi = 3.1414f;
    for (int it = 0; it < 12; ++it) {
      float al = 0.5f*(lo + hi);
      float ca = cosf(al);
      float arg = clamp1((ca - cq*cp) * rinv);
      float ax = fabsf(arg);
      float ac = sqrtf(fmaxf(0.f, 1.f - ax)) *
                 fmaf(ax, fmaf(ax, fmaf(ax, -0.0187293f, 0.0742610f), -0.2121144f), 1.5707288f);
      ac = (arg < 0.f) ? (PI - ac) : ac;
      float S = ac;
      #pragma unroll
      for (int off = 32; off; off >>= 1) S += __shfl_xor(S, off);
      float A = 2.f * S * (PI/64.f);
      if (A < At) lo = al; else hi = al;
    }
    if (lane == 0) {
      float chv = cosf(hi);
      if (tgt) cthr[row] = chv - 1e-5f;
      else     kthr[row] = 2.f*chv - 1.00002f;
    }
  } else {
    int tid = ((int)blockIdx.x - THRB_)*256 + threadIdx.x;
    if (tid < M_) {
      float th = pix[2*tid], ph = pix[2*tid+1];
      float st = sinf(th);
      float x = st*cosf(ph), y = st*sinf(ph), z = cosf(th);
      r_pix[tid] = make_float4(x, y, z, x*x + y*y + z*z);
      atomicAdd(&cnt[thbkt(th)], 1u);
    }
    int t2 = tid - M_;
    if (t2 >= 0 && t2 < B_*N_) {
      int b = t2 >> 12, n = t2 & (N_-1);
      const float* xb = xxx + b*3*N_;
      float th = xb[n], ph = xb[N_+n], ft = xb[2*N_+n];
      float st = sinf(th);
      r_los[t2] = make_float4(st*cosf(ph), st*sinf(ph), cosf(th), ft);
      atomicAdd(&cnt[256 + b*256 + thbkt(th)], 1u);
    }
    int t3 = tid - M_ - B_*N_;
    if (t3 >= 0 && t3 < B_*H_) gf[t3] = 0.0f;
  }
}

// ---------------- scan ----------------
__global__ __launch_bounds__(256) void scan_vC(
    const unsigned* __restrict__ cnt, int* __restrict__ pstart, int* __restrict__ lstart,
    unsigned* __restrict__ pcur, unsigned* __restrict__ lcur)
{
  __shared__ unsigned buf[256];
  const int t = threadIdx.x;
  for (int arr = 0; arr < 3; ++arr) {
    unsigned v = cnt[arr*256 + t];
    buf[t] = v;
    __syncthreads();
    for (int off = 1; off < 256; off <<= 1) {
      unsigned o = (t >= off) ? buf[t - off] : 0u;
      __syncthreads();
      buf[t] += o;
      __syncthreads();
    }
    unsigned incl = buf[t], excl = incl - v;
    if (arr == 0) {
      pstart[t] = (int)excl; if (t == 255) pstart[256] = (int)incl;
      pcur[t] = excl;
    } else {
      int b = arr - 1;
      lstart[b*257 + t] = (int)excl; if (t == 255) lstart[b*257 + 256] = (int)incl;
      lcur[b*256 + t] = excl;
    }
    __syncthreads();
  }
}

// ---------------- scatter ----------------
__global__ __launch_bounds__(256) void scatter_vC(
    const float* __restrict__ xxx, const float* __restrict__ pix,
    const float4* __restrict__ r_pix, const float4* __restrict__ r_los,
    unsigned* __restrict__ pcur, unsigned* __restrict__ lcur,
    float4* __restrict__ spix, int* __restrict__ sjdx,
    float4* __restrict__ slos, int* __restrict__ sldx)
{
  int tid = blockIdx.x * 256 + threadIdx.x;
  if (tid < M_) {
    int bkt = thbkt(pix[2*tid]);
    unsigned pos = atomicAdd(&pcur[bkt], 1u);
    spix[pos] = r_pix[tid];
    sjdx[pos] = tid;
  } else {
    int t2 = tid - M_;
    if (t2 < B_*N_) {
      int b = t2 >> 12, n = t2 & (N_-1);
      int bkt = thbkt(xxx[b*3*N_ + n]);
      unsigned pos = atomicAdd(&lcur[b*256 + bkt], 1u);
      slos[b*N_ + pos] = r_los[t2];
      sldx[b*N_ + pos] = n;
    }
  }
}

// ---------------- sampler vC: two-pass window scan, no candidate store (18 KB LDS) ----------------
__global__ __launch_bounds__(512) void sampler_vC(
    const float* __restrict__ pix,
    const float4* __restrict__ spix, const int* __restrict__ sjdx,
    const float4* __restrict__ slos, const int* __restrict__ sldx,
    const int* __restrict__ lstart, const float4* __restrict__ r_los,
    const float* __restrict__ cthr,
    const float* __restrict__ aw1, const float* __restrict__ ab1,
    const float* __restrict__ aw2, const float* __restrict__ ab2,
    float* __restrict__ pooled)
{
  __shared__ unsigned long long selKey[16][K_];     // 8 KB
  __shared__ unsigned long long bndK[16][BCAP2];    // 6 KB
  __shared__ unsigned hist[16][64];                 // 4 KB

  const int tid = threadIdx.x, wv = tid >> 6, lane = tid & 63;
  const int b  = blockIdx.y;
  const int srow0 = blockIdx.x*16 + wv*2, srow1 = srow0 + 1;
  const int r0 = wv*2, r1 = r0 + 1;
  const int m0 = sjdx[srow0], m1 = sjdx[srow1];
  const float4 p0 = spix[srow0], p1 = spix[srow1];
  const float thp0 = pix[2*m0], thp1 = pix[2*m1];
  float th0 = cthr[m0], th1 = cthr[m1];
  const float inv0 = 63.999f / (1.000001f - th0);
  const float inv1 = 63.999f / (1.000001f - th1);
  const float4* sl = slos + b * N_;
  const int* sx = sldx + b * N_;
  const float4* rl = r_los + b * N_;
  const int* ls = lstart + b * 257;
  const unsigned long long ltm = (1ull << lane) - 1ull;

  hist[r0][lane] = 0u; hist[r1][lane] = 0u;

  // union window bounds (shared by both passes)
  int jlo, jhi;
  {
    float al0 = acosf(clamp1(th0)), al1 = acosf(clamp1(th1));
    int blo = thbkt(fminf(thp0 - al0, thp1 - al1) - MG_);
    int bhi = thbkt(fmaxf(thp0 + al0, thp1 + al1) + MG_);
    jlo = ls[blo]; jhi = ls[bhi + 1];
  }

  // pass 1: count + histogram (no candidate store)
  unsigned cnt0 = 0, cnt1 = 0;
  for (int base = jlo; base < jhi; base += 64) {
    int pos = base + lane;
    bool act = pos < jhi;
    float c0 = -2.f, c1 = -2.f;
    if (act) {
      float4 v = sl[pos];
      c0 = clamp1(v.x*p0.x + v.y*p0.y + v.z*p0.z);
      c1 = clamp1(v.x*p1.x + v.y*p1.y + v.z*p1.z);
    }
    bool pr0 = c0 > th0, pr1 = c1 > th1;
    if (pr0) atomicAdd(&hist[r0][(int)((c0 - th0) * inv0)], 1u);
    if (pr1) atomicAdd(&hist[r1][(int)((c1 - th1) * inv1)], 1u);
    cnt0 += (unsigned)__popcll(__ballot(pr0));
    cnt1 += (unsigned)__popcll(__ballot(pr1));
  }

  for (int rr = 0; rr < 2; ++rr) {
    const int r = (rr == 0) ? r0 : r1;
    const int m = (rr == 0) ? m0 : m1;
    const float4 p = (rr == 0) ? p0 : p1;
    const float thp = (rr == 0) ? thp0 : thp1;
    float th = (rr == 0) ? th0 : th1;
    float inv = (rr == 0) ? inv0 : inv1;
    unsigned cn = (rr == 0) ? cnt0 : cnt1;
    int wlo = jlo, whi = jhi;

    // widen-retries: rescan with wider threshold, rebuild hist
    int tries = 0;
    while (cn < K_ && tries < 3) {
      th = 1.f - 1.6f*(1.f - th); ++tries;
      inv = 63.999f / (1.000001f - th);
      float al = acosf(clamp1(th));
      int blo = thbkt(thp - al - MG_), bhi = thbkt(thp + al + MG_);
      wlo = ls[blo]; whi = ls[bhi + 1];
      hist[r][lane] = 0u;
      cn = 0;
      for (int base = wlo; base < whi; base += 64) {
        int pos = base + lane;
        bool act = pos < whi;
        float c = -2.f;
        if (act) {
          float4 v = sl[pos];
          c = clamp1(v.x*p.x + v.y*p.y + v.z*p.z);
        }
        bool pr = c > th;
        if (pr) atomicAdd(&hist[r][(int)((c - th) * inv)], 1u);
        cn += (unsigned)__popcll(__ballot(pr));
      }
    }

    bool done = false;
    if (cn >= K_) {
      // suffix-scan over 64 bins (1/lane) -> threshold bin t, chi = cnt_gt(t)
      unsigned g = hist[r][lane], s = g;
      #pragma unroll
      for (int off = 1; off < 64; off <<= 1) {
        unsigned t2 = (unsigned)__shfl_down((int)s, off);
        s += (lane + off < 64) ? t2 : 0u;
      }
      unsigned snext = s - g;
      unsigned packed = (s >= K_ && snext < K_) ? (((unsigned)(lane+1) << 16) | snext) : 0u;
      #pragma unroll
      for (int off = 32; off; off >>= 1) {
        unsigned o = (unsigned)__shfl_xor((int)packed, off);
        packed = packed > o ? packed : o;
      }
      const int t = (int)(packed >> 16) - 1;
      const unsigned chi = packed & 0xFFFFu;
      const unsigned need = K_ - chi;

      // pass 2: collect winners (bin > t) + boundary keys (bin == t)
      unsigned hiC = 0, bdC = 0;
      for (int base = wlo; base < whi; base += 64) {
        int pos = base + lane;
        bool act = pos < whi;
        float c = -2.f; int n = 0;
        if (act) {
          float4 v = sl[pos]; n = sx[pos];
          c = clamp1(v.x*p.x + v.y*p.y + v.z*p.z);
        }
        int bin = (act && c > th) ? (int)((c - th) * inv) : -1;
        bool pHi = bin > t;
        bool pBd = bin == t;
        unsigned long long mH = __ballot(pHi);
        unsigned offH = (unsigned)__popcll(mH & ltm);
        if (pHi && hiC + offH < K_) selKey[r][hiC + offH] = spack(c, n);
        hiC += (unsigned)__popcll(mH);
        unsigned long long mB = __ballot(pBd);
        unsigned offB = (unsigned)__popcll(mB & ltm);
        if (pBd && bdC + offB < BCAP2) bndK[r][bdC + offB] = spack(c, n);
        bdC += (unsigned)__popcll(mB);
      }
      if (bdC <= (unsigned)BCAP2) {
        // boundary resolve: exact rank by (value desc, index asc)
        if (lane < (int)bdC) {
          unsigned long long ki = bndK[r][lane];
          int rank = 0;
          for (int j = 0; j < (int)bdC; ++j) rank += (bndK[r][j] > ki) ? 1 : 0;
          if ((unsigned)rank < need) selKey[r][chi + rank] = ki;
        }
        done = true;
      }
    }

    if (!done) {
      // ultimate exact: 64 rounds bounded argmax over full row
      unsigned long long prev = ~0ull;
      for (int rd = 0; rd < K_; ++rd) {
        unsigned long long best = 0ull;
        for (int i = 0; i < 64; ++i) {
          int n = lane + 64*i;
          float4 v = rl[n];
          float c = clamp1(v.x*p.x + v.y*p.y + v.z*p.z);
          unsigned long long k = spack(c, n);
          if (k < prev && k > best) best = k;
        }
        #pragma unroll
        for (int off = 1; off < 64; off <<= 1) {
          unsigned long long o = shflxor64(best, off);
          best = o > best ? o : best;
        }
        if (lane == 0) selKey[r][rd] = best;
        prev = best;
      }
    }

    // attention MLP + softmax + weighted pool
    {
      unsigned long long key = selKey[r][lane];
      int n = 4095 - (int)(key & 0xFFFull);
      float c = key2f((unsigned)(key >> 12));
      float xg = rl[n].w;
      float d  = acosf(clamp1(c));
      float acc = ab2[0];
      for (int s2 = 0; s2 < SH_; ++s2)
        acc += fmaxf(xg*aw1[s2] + d*aw1[SH_+s2] + ab1[s2], 0.f) * aw2[s2];
      float mx = acc;
      #pragma unroll
      for (int off = 32; off; off >>= 1) mx = fmaxf(mx, __shfl_xor(mx, off));
      float e = expf(acc - mx);
      float se = e, sxe = e * xg;
      #pragma unroll
      for (int off = 32; off; off >>= 1) { se += __shfl_xor(se, off); sxe += __shfl_xor(sxe, off); }
      if (lane == 0) pooled[b*M_ + m] = sxe / se;
    }
  }
}

// ---------------- knn vC (standalone, 30 KB LDS — v9/vA proven) ----------------
__global__ __launch_bounds__(512) void knn_vC(
    const float* __restrict__ pix,
    const float4* __restrict__ spix, const int* __restrict__ sjdx,
    const int* __restrict__ pstart, const float4* __restrict__ r_pix,
    const float* __restrict__ kthr, int* __restrict__ nbr)
{
  __shared__ unsigned long long cKey[16][KCAP];

  const int tid = threadIdx.x, wv = tid >> 6, lane = tid & 63;
  const int lr0 = wv*2;
  const int srow0 = blockIdx.x*16 + lr0, srow1 = srow0 + 1;
  const int i0 = sjdx[srow0], i1 = sjdx[srow1];
  const float4 p0 = spix[srow0], p1 = spix[srow1];
  const float thp0 = pix[2*i0], thp1 = pix[2*i1];
  const float t0 = kthr[i0], t1 = kthr[i1];
  const unsigned long long ltm = (1ull << lane) - 1ull;

  unsigned cnt0 = 0, cnt1 = 0;
  {
    float al0 = acosf(clamp1((t0 + 1.00002f)*0.5f));
    float al1 = acosf(clamp1((t1 + 1.00002f)*0.5f));
    int blo = thbkt(fminf(thp0 - al0, thp1 - al1) - MG_);
    int bhi = thbkt(fmaxf(thp0 + al0, thp1 + al1) + MG_);
    int jlo = pstart[blo], jhi = pstart[bhi + 1];
    for (int base = jlo; base < jhi; base += 64) {
      int pos = base + lane;
      bool act = pos < jhi;
      float s0 = -1e30f, s1 = -1e30f; int j = -1;
      if (act) {
        float4 v = spix[pos]; j = sjdx[pos];
        s0 = 2.f*(p0.x*v.x + p0.y*v.y + p0.z*v.z) - v.w;
        s1 = 2.f*(p1.x*v.x + p1.y*v.y + p1.z*v.z) - v.w;
      }
      bool pr0 = act && (j != i0) && (s0 > t0);
      bool pr1 = act && (j != i1) && (s1 > t1);
      unsigned long long mk0 = __ballot(pr0);
      if (mk0) {
        unsigned off = (unsigned)__popcll(mk0 & ltm);
        if (pr0 && cnt0 + off < KCAP) cKey[lr0][cnt0 + off] = kpack(s0, j);
        cnt0 += (unsigned)__popcll(mk0);
      }
      unsigned long long mk1 = __ballot(pr1);
      if (mk1) {
        unsigned off = (unsigned)__popcll(mk1 & ltm);
        if (pr1 && cnt1 + off < KCAP) cKey[lr0+1][cnt1 + off] = kpack(s1, j);
        cnt1 += (unsigned)__popcll(mk1);
      }
    }
  }

  for (int rr = 0; rr < 2; ++rr) {
    const int lr = lr0 + rr;
    const int i  = (rr == 0) ? i0 : i1;
    const float4 pi = (rr == 0) ? p0 : p1;
    const float thp = (rr == 0) ? thp0 : thp1;
    float th = (rr == 0) ? t0 : t1;
    unsigned cn = (rr == 0) ? cnt0 : cnt1;

    int tries = 0;
    while (cn < (unsigned)GK_ && tries < 3) {
      th = 1.6f*th - 0.6f; ++tries;
      float al = acosf(clamp1((th + 1.00002f)*0.5f));
      int blo = thbkt(thp - al - MG_), bhi = thbkt(thp + al + MG_);
      int jlo = pstart[blo], jhi = pstart[bhi + 1];
      cn = 0;
      for (int base = jlo; base < jhi; base += 64) {
        int pos = base + lane;
        bool act = pos < jhi;
        float s = -1e30f; int j = -1;
        if (act) {
          float4 v = spix[pos]; j = sjdx[pos];
          s = 2.f*(pi.x*v.x + pi.y*v.y + pi.z*v.z) - v.w;
        }
        bool pr = act && (j != i) && (s > th);
        unsigned long long mk = __ballot(pr);
        if (mk) {
          unsigned off = (unsigned)__popcll(mk & ltm);
          if (pr && cn + off < KCAP) cKey[lr][cn + off] = kpack(s, j);
          cn += (unsigned)__popcll(mk);
        }
      }
    }

    if (cn >= (unsigned)GK_ && cn <= (unsigned)KCAP) {
      unsigned long long pk[4];
      #pragma unroll
      for (int t2 = 0; t2 < 4; ++t2) {
        int idx = lane + 64*t2;
        pk[t2] = (idx < (int)cn) ? cKey[lr][idx] : 0ull;
      }
      for (int round = 0; round < GK_; ++round) {
        unsigned long long loc = pk[0]; int lt = 0;
        #pragma unroll
        for (int t2 = 1; t2 < 4; ++t2) if (pk[t2] > loc) { loc = pk[t2]; lt = t2; }
        unsigned long long best = loc;
        #pragma unroll
        for (int off = 1; off < 64; off <<= 1) {
          unsigned long long o = shflxor64(best, off);
          best = o > best ? o : best;
        }
        if (loc == best) {
          #pragma unroll
          for (int t2 = 0; t2 < 4; ++t2) if (t2 == lt) pk[t2] = 0ull;
        }
        if (lane == round) nbr[i*GK_ + round] = 16383 - (int)(best & 16383ull);
      }
    } else {
      unsigned long long prev = ~0ull;
      for (int rd = 0; rd < GK_; ++rd) {
        unsigned long long best = 0ull;
        for (int j = lane; j < M_; j += 64) {
          float4 v = r_pix[j];
          float s = 2.f*(pi.x*v.x + pi.y*v.y + pi.z*v.z) - v.w;
          if (j != i) {
            unsigned long long k = kpack(s, j);
            if (k < prev && k > best) best = k;
          }
        }
        #pragma unroll
        for (int off = 1; off < 64; off <<= 1) {
          unsigned long long o = shflxor64(best, off);
          best = o > best ? o : best;
        }
        if (lane == rd) nbr[i*GK_ + rd] = 16383 - (int)(best & 16383ull);
        prev = best;
      }
    }
  }
}

// ---------------- GNN layer 1 fused with proj (readlane matmul) ----------------
__global__ __launch_bounds__(256) void gnn1f_vC(
    const float* __restrict__ pooled, float* __restrict__ hout, const int* __restrict__ nbr,
    const float* __restrict__ pw, const float* __restrict__ pb,
    const float* __restrict__ relw, const float* __restrict__ relb,
    const float* __restrict__ rootw)
{
  __shared__ float wrel[H_*H_], wroot[H_*H_];
  const int tid = threadIdx.x;
  #pragma unroll
  for (int q = 0; q < 16; ++q) {
    int idx = tid + 256*q;
    wrel[idx]  = relw[idx];
    wroot[idx] = rootw[idx];
  }
  __syncthreads();

  const int lane = tid & 63;
  const int wave = tid >> 6;
  const int b = blockIdx.y;
  const int m0 = blockIdx.x * 16 + wave * 4;
  const float* pldb = pooled + (size_t)b * M_;
  const float pwl = pw[lane], pbl = pb[lane], rbl = relb[lane];

  float h[4], agg[4], acc[4];
  #pragma unroll
  for (int t = 0; t < 4; ++t) {
    int m = m0 + t;
    float ps = pldb[m];
    h[t] = fmaxf(ps*pwl + pbl, 0.f);
    float a = 0.f;
    #pragma unroll
    for (int k = 0; k < GK_; ++k) {
      int nb = nbr[m*GK_ + k];
      nb = nb < 0 ? 0 : (nb >= M_ ? M_-1 : nb);
      float pn = pldb[nb];
      a += fmaxf(pn*pwl + pbl, 0.f);
    }
    agg[t] = a;
    acc[t] = rbl;
  }
  #pragma unroll
  for (int c = 0; c < H_; ++c) {
    float wr = wrel[c*H_ + lane], wo = wroot[c*H_ + lane];
    #pragma unroll
    for (int t = 0; t < 4; ++t)
      acc[t] += rdlane(agg[t], c) * wr + rdlane(h[t], c) * wo;
  }
  #pragma unroll
  for (int t = 0; t < 4; ++t)
    hout[((size_t)b*M_ + m0 + t)*H_ + lane] = fmaxf(acc[t], 0.f);
}

// ---------------- GNN layer (generic, readlane matmul) ----------------
__global__ __launch_bounds__(256) void gnn_vC(
    const float* __restrict__ hin, float* __restrict__ hout, const int* __restrict__ nbr,
    const float* __restrict__ relw, const float* __restrict__ relb,
    const float* __restrict__ rootw)
{
  __shared__ float wrel[H_*H_], wroot[H_*H_];
  const int tid = threadIdx.x;
  #pragma unroll
  for (int q = 0; q < 16; ++q) {
    int idx = tid + 256*q;
    wrel[idx]  = relw[idx];
    wroot[idx] = rootw[idx];
  }
  __syncthreads();

  const int lane = tid & 63;
  const int wave = tid >> 6;
  const int b = blockIdx.y;
  const int m0 = blockIdx.x * 16 + wave * 4;
  const float* hb = hin + (size_t)b * M_ * H_;
  const float rbl = relb[lane];

  float h[4], agg[4], acc[4];
  #pragma unroll
  for (int t = 0; t < 4; ++t) {
    int m = m0 + t;
    h[t] = hb[m*H_ + lane];
    float a = 0.f;
    #pragma unroll
    for (int k = 0; k < GK_; ++k) {
      int nb = nbr[m*GK_ + k];
      nb = nb < 0 ? 0 : (nb >= M_ ? M_-1 : nb);
      a += hb[nb*H_ + lane];
    }
    agg[t] = a;
    acc[t] = rbl;
  }
  #pragma unroll
  for (int c = 0; c < H_; ++c) {
    float wr = wrel[c*H_ + lane], wo = wroot[c*H_ + lane];
    #pragma unroll
    for (int t = 0; t < 4; ++t)
      acc[t] += rdlane(agg[t], c) * wr + rdlane(h[t], c) * wo;
  }
  #pragma unroll
  for (int t = 0; t < 4; ++t)
    hout[((size_t)b*M_ + m0 + t)*H_ + lane] = fmaxf(acc[t], 0.f);
}

// ---------------- GNN layer 3 + fused global-mean reduce ----------------
__global__ __launch_bounds__(256) void gnn3r_vC(
    const float* __restrict__ hin, float* __restrict__ gf, const int* __restrict__ nbr,
    const float* __restrict__ relw, const float* __restrict__ relb,
    const float* __restrict__ rootw)
{
  __shared__ float wrel[H_*H_], wroot[H_*H_];
  __shared__ float gacc[H_];
  const int tid = threadIdx.x;
  #pragma unroll
  for (int q = 0; q < 16; ++q) {
    int idx = tid + 256*q;
    wrel[idx]  = relw[idx];
    wroot[idx] = rootw[idx];
  }
  if (tid < H_) gacc[tid] = 0.f;
  __syncthreads();

  const int lane = tid & 63;
  const int wave = tid >> 6;
  const int b = blockIdx.y;
  const int m0 = blockIdx.x * 16 + wave * 4;
  const float* hb = hin + (size_t)b * M_ * H_;
  const float rbl = relb[lane];

  float h[4], agg[4], acc[4];
  #pragma unroll
  for (int t = 0; t < 4; ++t) {
    int m = m0 + t;
    h[t] = hb[m*H_ + lane];
    float a = 0.f;
    #pragma unroll
    for (int k = 0; k < GK_; ++k) {
      int nb = nbr[m*GK_ + k];
      nb = nb < 0 ? 0 : (nb >= M_ ? M_-1 : nb);
      a += hb[nb*H_ + lane];
    }
    agg[t] = a;
    acc[t] = rbl;
  }
  #pragma unroll
  for (int c = 0; c < H_; ++c) {
    float wr = wrel[c*H_ + lane], wo = wroot[c*H_ + lane];
    #pragma unroll
    for (int t = 0; t < 4; ++t)
      acc[t] += rdlane(agg[t], c) * wr + rdlane(h[t], c) * wo;
  }
  float ps = fmaxf(acc[0], 0.f) + fmaxf(acc[1], 0.f) + fmaxf(acc[2], 0.f) + fmaxf(acc[3], 0.f);
  atomicAdd(&gacc[lane], ps);
  __syncthreads();
  if (tid < H_) atomicAdd(&gf[b*H_ + tid], gacc[tid]);
}

// ---------------- head ----------------
__global__ __launch_bounds__(256) void head_vC(
    const float* __restrict__ gf, const float* __restrict__ w1,
    const float* __restrict__ b1, const float* __restrict__ w2,
    const float* __restrict__ b2, float* __restrict__ out)
{
  __shared__ float gfm[B_][H_], hid[B_][H_];
  const int tid = threadIdx.x;
  if (tid < B_*H_) gfm[tid >> 6][tid & 63] = gf[tid] * (1.f / (float)M_);
  __syncthreads();
  if (tid < B_*H_) {
    int b = tid >> 6, j = tid & 63;
    float acc = b1[j];
    for (int c = 0; c < H_; ++c) acc += gfm[b][c] * w1[c*H_ + j];
    hid[b][j] = fmaxf(acc, 0.f);
  }
  __syncthreads();
  for (int t = tid; t < B_*NC_; t += 256) {
    int b = t / NC_, o = t - b*NC_;
    float acc = b2[o];
    for (int j = 0; j < H_; ++j) acc += hid[b][j] * w2[j*NC_ + o];
    out[t] = acc;
  }
}

extern "C" void kernel_launch(void* const* d_in, const int* in_sizes, int n_in,
                              void* d_out, int out_size, void* d_ws, size_t ws_size,
                              hipStream_t stream)
{
  float* out = (float*)d_out;

  const size_t need = (size_t)M_*16 + (size_t)B_*N_*16 + (size_t)B_*M_*4
                    + (size_t)M_*GK_*4 + 2*(size_t)B_*M_*H_*4 + (size_t)B_*H_*4;
  bool ok_ws = ws_size >= need;
  bool ok_in = (n_in == 15) && (out_size == B_*NC_)
            && in_sizes[0] == B_*3*N_ && in_sizes[1] == M_*2
            && in_sizes[2] == 2*SH_ && in_sizes[5] == 1
            && in_sizes[8] == 3*H_*H_ && in_sizes[13] == H_*NC_;
  if (!ok_ws || !ok_in) {
    sentinel_vC<<<(out_size + 255)/256, 256, 0, stream>>>(out, out_size, ok_in ? 42.f : 43.f);
    return;
  }

  const float* xxx    = (const float*)d_in[0];
  const float* pix    = (const float*)d_in[1];
  const float* att_w1 = (const float*)d_in[2];
  const float* att_b1 = (const float*)d_in[3];
  const float* att_w2 = (const float*)d_in[4];
  const float* att_b2 = (const float*)d_in[5];
  const float* proj_w = (const float*)d_in[6];
  const float* proj_b = (const float*)d_in[7];
  const float* rel_w  = (const float*)d_in[8];
  const float* rel_b  = (const float*)d_in[9];
  const float* root_w = (const float*)d_in[10];
  const float* out_w1 = (const float*)d_in[11];
  const float* out_b1 = (const float*)d_in[12];
  const float* out_w2 = (const float*)d_in[13];
  const float* out_b2 = (const float*)d_in[14];

  char* w = (char*)d_ws;
  float4* r_pix = (float4*)w;  w += (size_t)M_ * 16;
  float4* r_los = (float4*)w;  w += (size_t)B_ * N_ * 16;
  float*  pooled = (float*)w;  w += (size_t)B_ * M_ * 4;
  int*    nbr = (int*)w;       w += (size_t)M_ * GK_ * 4;
  float*  h0 = (float*)w;      w += (size_t)B_ * M_ * H_ * 4;
  float*  h1 = (float*)w;      w += (size_t)B_ * M_ * H_ * 4;
  float*  gf = (float*)w;      w += (size_t)B_ * H_ * 4;

  // sort/threshold scratch aliases h0 (dead until gnn layer 2 writes it)
  float*  kthr = h0;                                   // M
  float*  cthr = h0 + M_;                              // M
  float4* spix = (float4*)(h0 + 2*M_);                 // M float4
  int*    sjdx = (int*)(h0 + 6*M_);                    // M
  float4* slos = (float4*)(h0 + 7*M_);                 // B*N float4
  int*    sldx = (int*)(h0 + 7*M_ + 4*B_*N_);          // B*N
  unsigned* cnt = (unsigned*)(h0 + 7*M_ + 5*B_*N_);    // 768
  int*    pstart = (int*)(cnt + 768);                  // 257
  int*    lstart = pstart + 257;                       // 2*257
  unsigned* pcur = (unsigned*)(lstart + 514);          // 256
  unsigned* lcur = pcur + 256;                         // 512

  hipMemsetAsync(cnt, 0, 768*sizeof(unsigned), stream);
  prepthr_vC<<<THRB_ + PREPB_, 256, 0, stream>>>(xxx, pix, r_pix, r_los, gf, kthr, cthr, cnt);
  scan_vC<<<1, 256, 0, stream>>>(cnt, pstart, lstart, pcur, lcur);
  scatter_vC<<<(M_ + B_*N_ + 255)/256, 256, 0, stream>>>(xxx, pix, r_pix, r_los, pcur, lcur,
                                                         spix, sjdx, slos, sldx);
  sampler_vC<<<dim3(M_/16, B_), 512, 0, stream>>>(pix, spix, sjdx, slos, sldx, lstart, r_los,
                                                  cthr, att_w1, att_b1, att_w2, att_b2, pooled);
  knn_vC<<<M_/16, 512, 0, stream>>>(pix, spix, sjdx, pstart, r_pix, kthr, nbr);
  gnn1f_vC<<<dim3(M_/16, B_), 256, 0, stream>>>(pooled, h1, nbr, proj_w, proj_b,
                                                rel_w + 0*H_*H_, rel_b + 0*H_, root_w + 0*H_*H_);
  gnn_vC<<<dim3(M_/16, B_), 256, 0, stream>>>(h1, h0, nbr, rel_w + 1*H_*H_, rel_b + 1*H_, root_w + 1*H_*H_);
  gnn3r_vC<<<dim3(M_/16, B_), 256, 0, stream>>>(h0, gf, nbr, rel_w + 2*H_*H_, rel_b + 2*H_, root_w + 2*H_*H_);
  head_vC<<<1, 256, 0, stream>>>(gf, out_w1, out_b1, out_w2, out_b2, out);
}

// Round 13
// 269.898 us; speedup vs baseline: 1.0893x; 1.0657x over previous
//
#include <hip/hip_runtime.h>
#include <hip/hip_bf16.h>

#define B_ 2
#define N_ 4096
#define M_ 12288
#define K_ 64
#define SH_ 32
#define H_ 64
#define GK_ 8
#define NC_ 200

#define KCAP 128       // knn candidate cap (E=48, +11 sigma)
#define BCAP2 48       // sampler boundary cap
#define MG_ 0.01f      // theta-window safety margin (rad)
#define C256_ 81.48733086f   // 256/pi

static __device__ __forceinline__ unsigned f2key(float f) {
  unsigned b = __float_as_uint(f);
  return (b & 0x80000000u) ? ~b : (b | 0x80000000u);
}
static __device__ __forceinline__ float key2f(unsigned u) {
  unsigned b = (u & 0x80000000u) ? (u & 0x7fffffffu) : ~u;
  return __uint_as_float(b);
}
static __device__ __forceinline__ unsigned long long shflxor64(unsigned long long x, int m) {
  unsigned lo = (unsigned)x, hi = (unsigned)(x >> 32);
  lo = (unsigned)__shfl_xor((int)lo, m);
  hi = (unsigned)__shfl_xor((int)hi, m);
  return ((unsigned long long)hi << 32) | lo;
}
static __device__ __forceinline__ unsigned long long kpack(float s, int j) {
  return ((unsigned long long)f2key(s) << 14) | (unsigned)(16383 - j);
}
static __device__ __forceinline__ unsigned long long spack(float c, int n) {
  return ((unsigned long long)f2key(c) << 12) | (unsigned)(4095 - n);
}
static __device__ __forceinline__ int thbkt(float th) {
  int b = (int)(th * C256_);
  return b < 0 ? 0 : (b > 255 ? 255 : b);
}
static __device__ __forceinline__ float clamp1(float x) { return fminf(1.f, fmaxf(-1.f, x)); }
static __device__ __forceinline__ float rdlane(float v, int c) {
  return __uint_as_float((unsigned)__builtin_amdgcn_readlane((int)__float_as_uint(v), c));
}

// ---------------- sentinel ----------------
__global__ __launch_bounds__(256) void sentinel_vD(float* out, int n, float val) {
  int t = blockIdx.x * 256 + threadIdx.x;
  if (t < n) out[t] = val;
}

// ---------------- prep + thresholds + theta-band histograms ----------------
#define THRB_ 6144
#define PREPN_ (M_ + B_*N_ + B_*H_)
#define PREPB_ ((PREPN_ + 255)/256)

__global__ __launch_bounds__(256) void prepthr_vD(
    const float* __restrict__ xxx, const float* __restrict__ pix,
    float4* __restrict__ r_pix, float4* __restrict__ r_los, float* __restrict__ gf,
    float* __restrict__ kthr, float* __restrict__ cthr, unsigned* __restrict__ cnt)
{
  const float PI = 3.14159265358979f;
  if ((int)blockIdx.x < THRB_) {
    int gid  = blockIdx.x*4 + (threadIdx.x >> 6);
    int lane = threadIdx.x & 63;
    int tgt  = (gid >= M_) ? 1 : 0;
    int row  = gid - tgt*M_;
    float thp = pix[2*row];
    float cp = cosf(thp), sp = fmaxf(sinf(thp), 1e-6f);
    float thq = ((float)lane + 0.5f) * (PI/64.f);
    float sq = sinf(thq), cq = cosf(thq);
    float rinv = 1.0f / (sq * sp);
    // E targets: sampler 128 of N, knn 48 of M (retry ladder covers tails)
    float At = tgt ? (2.f*PI*PI*128.f/(float)N_) : (2.f*PI*PI*48.f/(float)M_);
    float lo = 1e-3f, hi = 3.1414f;
    for (int it = 0; it < 12; ++it) {
      float al = 0.5f*(lo + hi);
      float ca = cosf(al);
      float arg = clamp1((ca - cq*cp) * rinv);
      float ax = fabsf(arg);
      float ac = sqrtf(fmaxf(0.f, 1.f - ax)) *
                 fmaf(ax, fmaf(ax, fmaf(ax, -0.0187293f, 0.0742610f), -0.2121144f), 1.5707288f);
      ac = (arg < 0.f) ? (PI - ac) : ac;
      float S = ac;
      #pragma unroll
      for (int off = 32; off; off >>= 1) S += __shfl_xor(S, off);
      float A = 2.f * S * (PI/64.f);
      if (A < At) lo = al; else hi = al;
    }
    if (lane == 0) {
      float chv = cosf(hi);
      if (tgt) cthr[row] = chv - 1e-5f;
      else     kthr[row] = 2.f*chv - 1.00002f;
    }
  } else {
    int tid = ((int)blockIdx.x - THRB_)*256 + threadIdx.x;
    if (tid < M_) {
      float th = pix[2*tid], ph = pix[2*tid+1];
      float st = sinf(th);
      float x = st*cosf(ph), y = st*sinf(ph), z = cosf(th);
      r_pix[tid] = make_float4(x, y, z, x*x + y*y + z*z);
      atomicAdd(&cnt[thbkt(th)], 1u);
    }
    int t2 = tid - M_;
    if (t2 >= 0 && t2 < B_*N_) {
      int b = t2 >> 12, n = t2 & (N_-1);
      const float* xb = xxx + b*3*N_;
      float th = xb[n], ph = xb[N_+n], ft = xb[2*N_+n];
      float st = sinf(th);
      r_los[t2] = make_float4(st*cosf(ph), st*sinf(ph), cosf(th), ft);
      atomicAdd(&cnt[256 + b*256 + thbkt(th)], 1u);
    }
    int t3 = tid - M_ - B_*N_;
    if (t3 >= 0 && t3 < B_*H_) gf[t3] = 0.0f;
  }
}

// ---------------- scan ----------------
__global__ __launch_bounds__(256) void scan_vD(
    const unsigned* __restrict__ cnt, int* __restrict__ pstart, int* __restrict__ lstart,
    unsigned* __restrict__ pcur, unsigned* __restrict__ lcur)
{
  __shared__ unsigned buf[256];
  const int t = threadIdx.x;
  for (int arr = 0; arr < 3; ++arr) {
    unsigned v = cnt[arr*256 + t];
    buf[t] = v;
    __syncthreads();
    for (int off = 1; off < 256; off <<= 1) {
      unsigned o = (t >= off) ? buf[t - off] : 0u;
      __syncthreads();
      buf[t] += o;
      __syncthreads();
    }
    unsigned incl = buf[t], excl = incl - v;
    if (arr == 0) {
      pstart[t] = (int)excl; if (t == 255) pstart[256] = (int)incl;
      pcur[t] = excl;
    } else {
      int b = arr - 1;
      lstart[b*257 + t] = (int)excl; if (t == 255) lstart[b*257 + 256] = (int)incl;
      lcur[b*256 + t] = excl;
    }
    __syncthreads();
  }
}

// ---------------- scatter ----------------
__global__ __launch_bounds__(256) void scatter_vD(
    const float* __restrict__ xxx, const float* __restrict__ pix,
    const float4* __restrict__ r_pix, const float4* __restrict__ r_los,
    unsigned* __restrict__ pcur, unsigned* __restrict__ lcur,
    float4* __restrict__ spix, int* __restrict__ sjdx,
    float4* __restrict__ slos, int* __restrict__ sldx)
{
  int tid = blockIdx.x * 256 + threadIdx.x;
  if (tid < M_) {
    int bkt = thbkt(pix[2*tid]);
    unsigned pos = atomicAdd(&pcur[bkt], 1u);
    spix[pos] = r_pix[tid];
    sjdx[pos] = tid;
  } else {
    int t2 = tid - M_;
    if (t2 < B_*N_) {
      int b = t2 >> 12, n = t2 & (N_-1);
      int bkt = thbkt(xxx[b*3*N_ + n]);
      unsigned pos = atomicAdd(&lcur[b*256 + bkt], 1u);
      slos[b*N_ + pos] = r_los[t2];
      sldx[b*N_ + pos] = n;
    }
  }
}

// ---------------- sampler vD: pass1 hist + merged pass2 (both rows, one scan) ----------------
__global__ __launch_bounds__(512) void sampler_vD(
    const float* __restrict__ pix,
    const float4* __restrict__ spix, const int* __restrict__ sjdx,
    const float4* __restrict__ slos, const int* __restrict__ sldx,
    const int* __restrict__ lstart, const float4* __restrict__ r_los,
    const float* __restrict__ cthr,
    const float* __restrict__ aw1, const float* __restrict__ ab1,
    const float* __restrict__ aw2, const float* __restrict__ ab2,
    float* __restrict__ pooled)
{
  __shared__ unsigned long long selKey[16][K_];     // 8 KB
  __shared__ unsigned long long bndK[16][BCAP2];    // 6 KB
  __shared__ unsigned hist[16][64];                 // 4 KB

  const int tid = threadIdx.x, wv = tid >> 6, lane = tid & 63;
  const int b  = blockIdx.y;
  const int srow0 = blockIdx.x*16 + wv*2, srow1 = srow0 + 1;
  const int r0 = wv*2, r1 = r0 + 1;
  const int m0 = sjdx[srow0], m1 = sjdx[srow1];
  const float4 p0 = spix[srow0], p1 = spix[srow1];
  const float thp0 = pix[2*m0], thp1 = pix[2*m1];
  const float th0 = cthr[m0], th1 = cthr[m1];
  const float inv0 = 63.999f / (1.000001f - th0);
  const float inv1 = 63.999f / (1.000001f - th1);
  const float4* sl = slos + b * N_;
  const int* sx = sldx + b * N_;
  const float4* rl = r_los + b * N_;
  const int* ls = lstart + b * 257;
  const unsigned long long ltm = (1ull << lane) - 1ull;

  hist[r0][lane] = 0u; hist[r1][lane] = 0u;

  // union window bounds
  int jlo, jhi;
  {
    float al0 = acosf(clamp1(th0)), al1 = acosf(clamp1(th1));
    int blo = thbkt(fminf(thp0 - al0, thp1 - al1) - MG_);
    int bhi = thbkt(fmaxf(thp0 + al0, thp1 + al1) + MG_);
    jlo = ls[blo]; jhi = ls[bhi + 1];
  }

  // pass 1: count + histogram (no candidate store)
  unsigned cnt0 = 0, cnt1 = 0;
  for (int base = jlo; base < jhi; base += 64) {
    int pos = base + lane;
    bool act = pos < jhi;
    float c0 = -2.f, c1 = -2.f;
    if (act) {
      float4 v = sl[pos];
      c0 = clamp1(v.x*p0.x + v.y*p0.y + v.z*p0.z);
      c1 = clamp1(v.x*p1.x + v.y*p1.y + v.z*p1.z);
    }
    bool pr0 = c0 > th0, pr1 = c1 > th1;
    if (pr0) atomicAdd(&hist[r0][(int)((c0 - th0) * inv0)], 1u);
    if (pr1) atomicAdd(&hist[r1][(int)((c1 - th1) * inv1)], 1u);
    cnt0 += (unsigned)__popcll(__ballot(pr0));
    cnt1 += (unsigned)__popcll(__ballot(pr1));
  }

  // fast-path select params for rows with enough candidates
  bool ok[2] = { cnt0 >= K_, cnt1 >= K_ };
  int tsel[2]; unsigned chi_[2], need_[2];
  for (int rr = 0; rr < 2; ++rr) {
    tsel[rr] = 64; chi_[rr] = 0; need_[rr] = 0;
    if (ok[rr]) {
      const int r = (rr == 0) ? r0 : r1;
      unsigned g = hist[r][lane], s = g;
      #pragma unroll
      for (int off = 1; off < 64; off <<= 1) {
        unsigned t2 = (unsigned)__shfl_down((int)s, off);
        s += (lane + off < 64) ? t2 : 0u;
      }
      unsigned snext = s - g;
      unsigned packed = (s >= K_ && snext < K_) ? (((unsigned)(lane+1) << 16) | snext) : 0u;
      #pragma unroll
      for (int off = 32; off; off >>= 1) {
        unsigned o = (unsigned)__shfl_xor((int)packed, off);
        packed = packed > o ? packed : o;
      }
      tsel[rr] = (int)(packed >> 16) - 1;
      chi_[rr] = packed & 0xFFFFu;
      need_[rr] = K_ - chi_[rr];
    }
  }

  // merged pass 2: one scan collecting winners + boundary for both ok rows
  bool done[2] = { false, false };
  if (ok[0] || ok[1]) {
    unsigned hiC0 = 0, bdC0 = 0, hiC1 = 0, bdC1 = 0;
    for (int base = jlo; base < jhi; base += 64) {
      int pos = base + lane;
      bool act = pos < jhi;
      float c0 = -2.f, c1 = -2.f; int n = 0;
      if (act) {
        float4 v = sl[pos]; n = sx[pos];
        c0 = clamp1(v.x*p0.x + v.y*p0.y + v.z*p0.z);
        c1 = clamp1(v.x*p1.x + v.y*p1.y + v.z*p1.z);
      }
      if (ok[0]) {
        int bin = (act && c0 > th0) ? (int)((c0 - th0) * inv0) : -1;
        bool pHi = bin > tsel[0], pBd = bin == tsel[0];
        unsigned long long mH = __ballot(pHi);
        unsigned offH = (unsigned)__popcll(mH & ltm);
        if (pHi && hiC0 + offH < K_) selKey[r0][hiC0 + offH] = spack(c0, n);
        hiC0 += (unsigned)__popcll(mH);
        unsigned long long mB = __ballot(pBd);
        unsigned offB = (unsigned)__popcll(mB & ltm);
        if (pBd && bdC0 + offB < BCAP2) bndK[r0][bdC0 + offB] = spack(c0, n);
        bdC0 += (unsigned)__popcll(mB);
      }
      if (ok[1]) {
        int bin = (act && c1 > th1) ? (int)((c1 - th1) * inv1) : -1;
        bool pHi = bin > tsel[1], pBd = bin == tsel[1];
        unsigned long long mH = __ballot(pHi);
        unsigned offH = (unsigned)__popcll(mH & ltm);
        if (pHi && hiC1 + offH < K_) selKey[r1][hiC1 + offH] = spack(c1, n);
        hiC1 += (unsigned)__popcll(mH);
        unsigned long long mB = __ballot(pBd);
        unsigned offB = (unsigned)__popcll(mB & ltm);
        if (pBd && bdC1 + offB < BCAP2) bndK[r1][bdC1 + offB] = spack(c1, n);
        bdC1 += (unsigned)__popcll(mB);
      }
    }
    // boundary resolve per ok row
    for (int rr = 0; rr < 2; ++rr) {
      if (!ok[rr]) continue;
      unsigned bdC = (rr == 0) ? bdC0 : bdC1;
      const int r = (rr == 0) ? r0 : r1;
      if (bdC <= (unsigned)BCAP2) {
        if (lane < (int)bdC) {
          unsigned long long ki = bndK[r][lane];
          int rank = 0;
          for (int j = 0; j < (int)bdC; ++j) rank += (bndK[r][j] > ki) ? 1 : 0;
          if ((unsigned)rank < need_[rr]) selKey[r][chi_[rr] + rank] = ki;
        }
        done[rr] = true;
      }
    }
  }

  for (int rr = 0; rr < 2; ++rr) {
    const int r = (rr == 0) ? r0 : r1;
    const int m = (rr == 0) ? m0 : m1;
    const float4 p = (rr == 0) ? p0 : p1;
    const float thp = (rr == 0) ? thp0 : thp1;

    if (!done[rr]) {
      // slow path (rare): retry ladder + per-row hist select, else ultimate
      float th = (rr == 0) ? th0 : th1;
      float inv = (rr == 0) ? inv0 : inv1;
      unsigned cn = (rr == 0) ? cnt0 : cnt1;
      int wlo = jlo, whi = jhi;

      int tries = 0;
      while (cn < K_ && tries < 3) {
        th = 1.f - 1.6f*(1.f - th); ++tries;
        inv = 63.999f / (1.000001f - th);
        float al = acosf(clamp1(th));
        int blo = thbkt(thp - al - MG_), bhi = thbkt(thp + al + MG_);
        wlo = ls[blo]; whi = ls[bhi + 1];
        hist[r][lane] = 0u;
        cn = 0;
        for (int base = wlo; base < whi; base += 64) {
          int pos = base + lane;
          bool act = pos < whi;
          float c = -2.f;
          if (act) {
            float4 v = sl[pos];
            c = clamp1(v.x*p.x + v.y*p.y + v.z*p.z);
          }
          bool pr = c > th;
          if (pr) atomicAdd(&hist[r][(int)((c - th) * inv)], 1u);
          cn += (unsigned)__popcll(__ballot(pr));
        }
      }

      bool fin = false;
      if (cn >= K_) {
        unsigned g = hist[r][lane], s = g;
        #pragma unroll
        for (int off = 1; off < 64; off <<= 1) {
          unsigned t2 = (unsigned)__shfl_down((int)s, off);
          s += (lane + off < 64) ? t2 : 0u;
        }
        unsigned snext = s - g;
        unsigned packed = (s >= K_ && snext < K_) ? (((unsigned)(lane+1) << 16) | snext) : 0u;
        #pragma unroll
        for (int off = 32; off; off >>= 1) {
          unsigned o = (unsigned)__shfl_xor((int)packed, off);
          packed = packed > o ? packed : o;
        }
        const int t = (int)(packed >> 16) - 1;
        const unsigned chi = packed & 0xFFFFu;
        const unsigned need = K_ - chi;

        unsigned hiC = 0, bdC = 0;
        for (int base = wlo; base < whi; base += 64) {
          int pos = base + lane;
          bool act = pos < whi;
          float c = -2.f; int n = 0;
          if (act) {
            float4 v = sl[pos]; n = sx[pos];
            c = clamp1(v.x*p.x + v.y*p.y + v.z*p.z);
          }
          int bin = (act && c > th) ? (int)((c - th) * inv) : -1;
          bool pHi = bin > t;
          bool pBd = bin == t;
          unsigned long long mH = __ballot(pHi);
          unsigned offH = (unsigned)__popcll(mH & ltm);
          if (pHi && hiC + offH < K_) selKey[r][hiC + offH] = spack(c, n);
          hiC += (unsigned)__popcll(mH);
          unsigned long long mB = __ballot(pBd);
          unsigned offB = (unsigned)__popcll(mB & ltm);
          if (pBd && bdC + offB < BCAP2) bndK[r][bdC + offB] = spack(c, n);
          bdC += (unsigned)__popcll(mB);
        }
        if (bdC <= (unsigned)BCAP2) {
          if (lane < (int)bdC) {
            unsigned long long ki = bndK[r][lane];
            int rank = 0;
            for (int j = 0; j < (int)bdC; ++j) rank += (bndK[r][j] > ki) ? 1 : 0;
            if ((unsigned)rank < need) selKey[r][chi + rank] = ki;
          }
          fin = true;
        }
      }

      if (!fin) {
        // ultimate exact: 64 rounds bounded argmax over full row
        unsigned long long prev = ~0ull;
        for (int rd = 0; rd < K_; ++rd) {
          unsigned long long best = 0ull;
          for (int i = 0; i < 64; ++i) {
            int n = lane + 64*i;
            float4 v = rl[n];
            float c = clamp1(v.x*p.x + v.y*p.y + v.z*p.z);
            unsigned long long k = spack(c, n);
            if (k < prev && k > best) best = k;
          }
          #pragma unroll
          for (int off = 1; off < 64; off <<= 1) {
            unsigned long long o = shflxor64(best, off);
            best = o > best ? o : best;
          }
          if (lane == 0) selKey[r][rd] = best;
          prev = best;
        }
      }
    }

    // attention MLP + softmax + weighted pool
    {
      unsigned long long key = selKey[r][lane];
      int n = 4095 - (int)(key & 0xFFFull);
      float c = key2f((unsigned)(key >> 12));
      float xg = rl[n].w;
      float d  = acosf(clamp1(c));
      float acc = ab2[0];
      for (int s2 = 0; s2 < SH_; ++s2)
        acc += fmaxf(xg*aw1[s2] + d*aw1[SH_+s2] + ab1[s2], 0.f) * aw2[s2];
      float mx = acc;
      #pragma unroll
      for (int off = 32; off; off >>= 1) mx = fmaxf(mx, __shfl_xor(mx, off));
      float e = expf(acc - mx);
      float se = e, sxe = e * xg;
      #pragma unroll
      for (int off = 32; off; off >>= 1) { se += __shfl_xor(se, off); sxe += __shfl_xor(sxe, off); }
      if (lane == 0) pooled[b*M_ + m] = sxe / se;
    }
  }
}

// ---------------- knn vD (KCAP=128, 16 KB LDS) ----------------
__global__ __launch_bounds__(512) void knn_vD(
    const float* __restrict__ pix,
    const float4* __restrict__ spix, const int* __restrict__ sjdx,
    const int* __restrict__ pstart, const float4* __restrict__ r_pix,
    const float* __restrict__ kthr, int* __restrict__ nbr)
{
  __shared__ unsigned long long cKey[16][KCAP];

  const int tid = threadIdx.x, wv = tid >> 6, lane = tid & 63;
  const int lr0 = wv*2;
  const int srow0 = blockIdx.x*16 + lr0, srow1 = srow0 + 1;
  const int i0 = sjdx[srow0], i1 = sjdx[srow1];
  const float4 p0 = spix[srow0], p1 = spix[srow1];
  const float thp0 = pix[2*i0], thp1 = pix[2*i1];
  const float t0 = kthr[i0], t1 = kthr[i1];
  const unsigned long long ltm = (1ull << lane) - 1ull;

  unsigned cnt0 = 0, cnt1 = 0;
  {
    float al0 = acosf(clamp1((t0 + 1.00002f)*0.5f));
    float al1 = acosf(clamp1((t1 + 1.00002f)*0.5f));
    int blo = thbkt(fminf(thp0 - al0, thp1 - al1) - MG_);
    int bhi = thbkt(fmaxf(thp0 + al0, thp1 + al1) + MG_);
    int jlo = pstart[blo], jhi = pstart[bhi + 1];
    for (int base = jlo; base < jhi; base += 64) {
      int pos = base + lane;
      bool act = pos < jhi;
      float s0 = -1e30f, s1 = -1e30f; int j = -1;
      if (act) {
        float4 v = spix[pos]; j = sjdx[pos];
        s0 = 2.f*(p0.x*v.x + p0.y*v.y + p0.z*v.z) - v.w;
        s1 = 2.f*(p1.x*v.x + p1.y*v.y + p1.z*v.z) - v.w;
      }
      bool pr0 = act && (j != i0) && (s0 > t0);
      bool pr1 = act && (j != i1) && (s1 > t1);
      unsigned long long mk0 = __ballot(pr0);
      if (mk0) {
        unsigned off = (unsigned)__popcll(mk0 & ltm);
        if (pr0 && cnt0 + off < KCAP) cKey[lr0][cnt0 + off] = kpack(s0, j);
        cnt0 += (unsigned)__popcll(mk0);
      }
      unsigned long long mk1 = __ballot(pr1);
      if (mk1) {
        unsigned off = (unsigned)__popcll(mk1 & ltm);
        if (pr1 && cnt1 + off < KCAP) cKey[lr0+1][cnt1 + off] = kpack(s1, j);
        cnt1 += (unsigned)__popcll(mk1);
      }
    }
  }

  for (int rr = 0; rr < 2; ++rr) {
    const int lr = lr0 + rr;
    const int i  = (rr == 0) ? i0 : i1;
    const float4 pi = (rr == 0) ? p0 : p1;
    const float thp = (rr == 0) ? thp0 : thp1;
    float th = (rr == 0) ? t0 : t1;
    unsigned cn = (rr == 0) ? cnt0 : cnt1;

    int tries = 0;
    while (cn < (unsigned)GK_ && tries < 3) {
      th = 1.6f*th - 0.6f; ++tries;
      float al = acosf(clamp1((th + 1.00002f)*0.5f));
      int blo = thbkt(thp - al - MG_), bhi = thbkt(thp + al + MG_);
      int jlo = pstart[blo], jhi = pstart[bhi + 1];
      cn = 0;
      for (int base = jlo; base < jhi; base += 64) {
        int pos = base + lane;
        bool act = pos < jhi;
        float s = -1e30f; int j = -1;
        if (act) {
          float4 v = spix[pos]; j = sjdx[pos];
          s = 2.f*(pi.x*v.x + pi.y*v.y + pi.z*v.z) - v.w;
        }
        bool pr = act && (j != i) && (s > th);
        unsigned long long mk = __ballot(pr);
        if (mk) {
          unsigned off = (unsigned)__popcll(mk & ltm);
          if (pr && cn + off < KCAP) cKey[lr][cn + off] = kpack(s, j);
          cn += (unsigned)__popcll(mk);
        }
      }
    }

    if (cn >= (unsigned)GK_ && cn <= (unsigned)KCAP) {
      unsigned long long pk[2];
      #pragma unroll
      for (int t2 = 0; t2 < 2; ++t2) {
        int idx = lane + 64*t2;
        pk[t2] = (idx < (int)cn) ? cKey[lr][idx] : 0ull;
      }
      for (int round = 0; round < GK_; ++round) {
        unsigned long long loc = pk[0]; int lt = 0;
        if (pk[1] > loc) { loc = pk[1]; lt = 1; }
        unsigned long long best = loc;
        #pragma unroll
        for (int off = 1; off < 64; off <<= 1) {
          unsigned long long o = shflxor64(best, off);
          best = o > best ? o : best;
        }
        if (loc == best) pk[lt] = 0ull;
        if (lane == round) nbr[i*GK_ + round] = 16383 - (int)(best & 16383ull);
      }
    } else {
      unsigned long long prev = ~0ull;
      for (int rd = 0; rd < GK_; ++rd) {
        unsigned long long best = 0ull;
        for (int j = lane; j < M_; j += 64) {
          float4 v = r_pix[j];
          float s = 2.f*(pi.x*v.x + pi.y*v.y + pi.z*v.z) - v.w;
          if (j != i) {
            unsigned long long k = kpack(s, j);
            if (k < prev && k > best) best = k;
          }
        }
        #pragma unroll
        for (int off = 1; off < 64; off <<= 1) {
          unsigned long long o = shflxor64(best, off);
          best = o > best ? o : best;
        }
        if (lane == rd) nbr[i*GK_ + rd] = 16383 - (int)(best & 16383ull);
        prev = best;
      }
    }
  }
}

// ---------------- GNN layer 1 fused with proj (readlane matmul) ----------------
__global__ __launch_bounds__(256) void gnn1f_vD(
    const float* __restrict__ pooled, float* __restrict__ hout, const int* __restrict__ nbr,
    const float* __restrict__ pw, const float* __restrict__ pb,
    const float* __restrict__ relw, const float* __restrict__ relb,
    const float* __restrict__ rootw)
{
  __shared__ float wrel[H_*H_], wroot[H_*H_];
  const int tid = threadIdx.x;
  #pragma unroll
  for (int q = 0; q < 16; ++q) {
    int idx = tid + 256*q;
    wrel[idx]  = relw[idx];
    wroot[idx] = rootw[idx];
  }
  __syncthreads();

  const int lane = tid & 63;
  const int wave = tid >> 6;
  const int b = blockIdx.y;
  const int m0 = blockIdx.x * 16 + wave * 4;
  const float* pldb = pooled + (size_t)b * M_;
  const float pwl = pw[lane], pbl = pb[lane], rbl = relb[lane];

  float h[4], agg[4], acc[4];
  #pragma unroll
  for (int t = 0; t < 4; ++t) {
    int m = m0 + t;
    float ps = pldb[m];
    h[t] = fmaxf(ps*pwl + pbl, 0.f);
    float a = 0.f;
    #pragma unroll
    for (int k = 0; k < GK_; ++k) {
      int nb = nbr[m*GK_ + k];
      nb = nb < 0 ? 0 : (nb >= M_ ? M_-1 : nb);
      float pn = pldb[nb];
      a += fmaxf(pn*pwl + pbl, 0.f);
    }
    agg[t] = a;
    acc[t] = rbl;
  }
  #pragma unroll
  for (int c = 0; c < H_; ++c) {
    float wr = wrel[c*H_ + lane], wo = wroot[c*H_ + lane];
    #pragma unroll
    for (int t = 0; t < 4; ++t)
      acc[t] += rdlane(agg[t], c) * wr + rdlane(h[t], c) * wo;
  }
  #pragma unroll
  for (int t = 0; t < 4; ++t)
    hout[((size_t)b*M_ + m0 + t)*H_ + lane] = fmaxf(acc[t], 0.f);
}

// ---------------- GNN layer (generic, readlane matmul) ----------------
__global__ __launch_bounds__(256) void gnn_vD(
    const float* __restrict__ hin, float* __restrict__ hout, const int* __restrict__ nbr,
    const float* __restrict__ relw, const float* __restrict__ relb,
    const float* __restrict__ rootw)
{
  __shared__ float wrel[H_*H_], wroot[H_*H_];
  const int tid = threadIdx.x;
  #pragma unroll
  for (int q = 0; q < 16; ++q) {
    int idx = tid + 256*q;
    wrel[idx]  = relw[idx];
    wroot[idx] = rootw[idx];
  }
  __syncthreads();

  const int lane = tid & 63;
  const int wave = tid >> 6;
  const int b = blockIdx.y;
  const int m0 = blockIdx.x * 16 + wave * 4;
  const float* hb = hin + (size_t)b * M_ * H_;
  const float rbl = relb[lane];

  float h[4], agg[4], acc[4];
  #pragma unroll
  for (int t = 0; t < 4; ++t) {
    int m = m0 + t;
    h[t] = hb[m*H_ + lane];
    float a = 0.f;
    #pragma unroll
    for (int k = 0; k < GK_; ++k) {
      int nb = nbr[m*GK_ + k];
      nb = nb < 0 ? 0 : (nb >= M_ ? M_-1 : nb);
      a += hb[nb*H_ + lane];
    }
    agg[t] = a;
    acc[t] = rbl;
  }
  #pragma unroll
  for (int c = 0; c < H_; ++c) {
    float wr = wrel[c*H_ + lane], wo = wroot[c*H_ + lane];
    #pragma unroll
    for (int t = 0; t < 4; ++t)
      acc[t] += rdlane(agg[t], c) * wr + rdlane(h[t], c) * wo;
  }
  #pragma unroll
  for (int t = 0; t < 4; ++t)
    hout[((size_t)b*M_ + m0 + t)*H_ + lane] = fmaxf(acc[t], 0.f);
}

// ---------------- GNN layer 3 + fused global-mean reduce ----------------
__global__ __launch_bounds__(256) void gnn3r_vD(
    const float* __restrict__ hin, float* __restrict__ gf, const int* __restrict__ nbr,
    const float* __restrict__ relw, const float* __restrict__ relb,
    const float* __restrict__ rootw)
{
  __shared__ float wrel[H_*H_], wroot[H_*H_];
  __shared__ float gacc[H_];
  const int tid = threadIdx.x;
  #pragma unroll
  for (int q = 0; q < 16; ++q) {
    int idx = tid + 256*q;
    wrel[idx]  = relw[idx];
    wroot[idx] = rootw[idx];
  }
  if (tid < H_) gacc[tid] = 0.f;
  __syncthreads();

  const int lane = tid & 63;
  const int wave = tid >> 6;
  const int b = blockIdx.y;
  const int m0 = blockIdx.x * 16 + wave * 4;
  const float* hb = hin + (size_t)b * M_ * H_;
  const float rbl = relb[lane];

  float h[4], agg[4], acc[4];
  #pragma unroll
  for (int t = 0; t < 4; ++t) {
    int m = m0 + t;
    h[t] = hb[m*H_ + lane];
    float a = 0.f;
    #pragma unroll
    for (int k = 0; k < GK_; ++k) {
      int nb = nbr[m*GK_ + k];
      nb = nb < 0 ? 0 : (nb >= M_ ? M_-1 : nb);
      a += hb[nb*H_ + lane];
    }
    agg[t] = a;
    acc[t] = rbl;
  }
  #pragma unroll
  for (int c = 0; c < H_; ++c) {
    float wr = wrel[c*H_ + lane], wo = wroot[c*H_ + lane];
    #pragma unroll
    for (int t = 0; t < 4; ++t)
      acc[t] += rdlane(agg[t], c) * wr + rdlane(h[t], c) * wo;
  }
  float ps = fmaxf(acc[0], 0.f) + fmaxf(acc[1], 0.f) + fmaxf(acc[2], 0.f) + fmaxf(acc[3], 0.f);
  atomicAdd(&gacc[lane], ps);
  __syncthreads();
  if (tid < H_) atomicAdd(&gf[b*H_ + tid], gacc[tid]);
}

// ---------------- head ----------------
__global__ __launch_bounds__(256) void head_vD(
    const float* __restrict__ gf, const float* __restrict__ w1,
    const float* __restrict__ b1, const float* __restrict__ w2,
    const float* __restrict__ b2, float* __restrict__ out)
{
  __shared__ float gfm[B_][H_], hid[B_][H_];
  const int tid = threadIdx.x;
  if (tid < B_*H_) gfm[tid >> 6][tid & 63] = gf[tid] * (1.f / (float)M_);
  __syncthreads();
  if (tid < B_*H_) {
    int b = tid >> 6, j = tid & 63;
    float acc = b1[j];
    for (int c = 0; c < H_; ++c) acc += gfm[b][c] * w1[c*H_ + j];
    hid[b][j] = fmaxf(acc, 0.f);
  }
  __syncthreads();
  for (int t = tid; t < B_*NC_; t += 256) {
    int b = t / NC_, o = t - b*NC_;
    float acc = b2[o];
    for (int j = 0; j < H_; ++j) acc += hid[b][j] * w2[j*NC_ + o];
    out[t] = acc;
  }
}

extern "C" void kernel_launch(void* const* d_in, const int* in_sizes, int n_in,
                              void* d_out, int out_size, void* d_ws, size_t ws_size,
                              hipStream_t stream)
{
  float* out = (float*)d_out;

  const size_t need = (size_t)M_*16 + (size_t)B_*N_*16 + (size_t)B_*M_*4
                    + (size_t)M_*GK_*4 + 2*(size_t)B_*M_*H_*4 + (size_t)B_*H_*4;
  bool ok_ws = ws_size >= need;
  bool ok_in = (n_in == 15) && (out_size == B_*NC_)
            && in_sizes[0] == B_*3*N_ && in_sizes[1] == M_*2
            && in_sizes[2] == 2*SH_ && in_sizes[5] == 1
            && in_sizes[8] == 3*H_*H_ && in_sizes[13] == H_*NC_;
  if (!ok_ws || !ok_in) {
    sentinel_vD<<<(out_size + 255)/256, 256, 0, stream>>>(out, out_size, ok_in ? 42.f : 43.f);
    return;
  }

  const float* xxx    = (const float*)d_in[0];
  const float* pix    = (const float*)d_in[1];
  const float* att_w1 = (const float*)d_in[2];
  const float* att_b1 = (const float*)d_in[3];
  const float* att_w2 = (const float*)d_in[4];
  const float* att_b2 = (const float*)d_in[5];
  const float* proj_w = (const float*)d_in[6];
  const float* proj_b = (const float*)d_in[7];
  const float* rel_w  = (const float*)d_in[8];
  const float* rel_b  = (const float*)d_in[9];
  const float* root_w = (const float*)d_in[10];
  const float* out_w1 = (const float*)d_in[11];
  const float* out_b1 = (const float*)d_in[12];
  const float* out_w2 = (const float*)d_in[13];
  const float* out_b2 = (const float*)d_in[14];

  char* w = (char*)d_ws;
  float4* r_pix = (float4*)w;  w += (size_t)M_ * 16;
  float4* r_los = (float4*)w;  w += (size_t)B_ * N_ * 16;
  float*  pooled = (float*)w;  w += (size_t)B_ * M_ * 4;
  int*    nbr = (int*)w;       w += (size_t)M_ * GK_ * 4;
  float*  h0 = (float*)w;      w += (size_t)B_ * M_ * H_ * 4;
  float*  h1 = (float*)w;      w += (size_t)B_ * M_ * H_ * 4;
  float*  gf = (float*)w;      w += (size_t)B_ * H_ * 4;

  // sort/threshold scratch aliases h0 (dead until gnn layer 2 writes it)
  float*  kthr = h0;                                   // M
  float*  cthr = h0 + M_;                              // M
  float4* spix = (float4*)(h0 + 2*M_);                 // M float4
  int*    sjdx = (int*)(h0 + 6*M_);                    // M
  float4* slos = (float4*)(h0 + 7*M_);                 // B*N float4
  int*    sldx = (int*)(h0 + 7*M_ + 4*B_*N_);          // B*N
  unsigned* cnt = (unsigned*)(h0 + 7*M_ + 5*B_*N_);    // 768
  int*    pstart = (int*)(cnt + 768);                  // 257
  int*    lstart = pstart + 257;                       // 2*257
  unsigned* pcur = (unsigned*)(lstart + 514);          // 256
  unsigned* lcur = pcur + 256;                         // 512

  hipMemsetAsync(cnt, 0, 768*sizeof(unsigned), stream);
  prepthr_vD<<<THRB_ + PREPB_, 256, 0, stream>>>(xxx, pix, r_pix, r_los, gf, kthr, cthr, cnt);
  scan_vD<<<1, 256, 0, stream>>>(cnt, pstart, lstart, pcur, lcur);
  scatter_vD<<<(M_ + B_*N_ + 255)/256, 256, 0, stream>>>(xxx, pix, r_pix, r_los, pcur, lcur,
                                                         spix, sjdx, slos, sldx);
  sampler_vD<<<dim3(M_/16, B_), 512, 0, stream>>>(pix, spix, sjdx, slos, sldx, lstart, r_los,
                                                  cthr, att_w1, att_b1, att_w2, att_b2, pooled);
  knn_vD<<<M_/16, 512, 0, stream>>>(pix, spix, sjdx, pstart, r_pix, kthr, nbr);
  gnn1f_vD<<<dim3(M_/16, B_), 256, 0, stream>>>(pooled, h1, nbr, proj_w, proj_b,
                                                rel_w + 0*H_*H_, rel_b + 0*H_, root_w + 0*H_*H_);
  gnn_vD<<<dim3(M_/16, B_), 256, 0, stream>>>(h1, h0, nbr, rel_w + 1*H_*H_, rel_b + 1*H_, root_w + 1*H_*H_);
  gnn3r_vD<<<dim3(M_/16, B_), 256, 0, stream>>>(h0, gf, nbr, rel_w + 2*H_*H_, rel_b + 2*H_, root_w + 2*H_*H_);
  head_vD<<<1, 256, 0, stream>>>(gf, out_w1, out_b1, out_w2, out_b2, out);
}

// Round 14
// 254.360 us; speedup vs baseline: 1.1559x; 1.0611x over previous
//
#include <hip/hip_runtime.h>
#include <hip/hip_bf16.h>

#define B_ 2
#define N_ 4096
#define M_ 12288
#define K_ 64
#define SH_ 32
#define H_ 64
#define GK_ 8
#define NC_ 200

#define KCAP 128       // knn candidate cap (E=48, +11 sigma)
#define BCAP2 48       // sampler boundary cap
#define MG_ 0.01f      // theta-window safety margin (rad)
#define C256_ 81.48733086f   // 256/pi

static __device__ __forceinline__ unsigned f2key(float f) {
  unsigned b = __float_as_uint(f);
  return (b & 0x80000000u) ? ~b : (b | 0x80000000u);
}
static __device__ __forceinline__ float key2f(unsigned u) {
  unsigned b = (u & 0x80000000u) ? (u & 0x7fffffffu) : ~u;
  return __uint_as_float(b);
}
static __device__ __forceinline__ unsigned long long shflxor64(unsigned long long x, int m) {
  unsigned lo = (unsigned)x, hi = (unsigned)(x >> 32);
  lo = (unsigned)__shfl_xor((int)lo, m);
  hi = (unsigned)__shfl_xor((int)hi, m);
  return ((unsigned long long)hi << 32) | lo;
}
static __device__ __forceinline__ unsigned long long kpack(float s, int j) {
  return ((unsigned long long)f2key(s) << 14) | (unsigned)(16383 - j);
}
static __device__ __forceinline__ unsigned long long spack(float c, int n) {
  return ((unsigned long long)f2key(c) << 12) | (unsigned)(4095 - n);
}
static __device__ __forceinline__ int thbkt(float th) {
  int b = (int)(th * C256_);
  return b < 0 ? 0 : (b > 255 ? 255 : b);
}
static __device__ __forceinline__ float clamp1(float x) { return fminf(1.f, fmaxf(-1.f, x)); }
static __device__ __forceinline__ float rdlane(float v, int c) {
  return __uint_as_float((unsigned)__builtin_amdgcn_readlane((int)__float_as_uint(v), c));
}

// ---------------- sentinel ----------------
__global__ __launch_bounds__(256) void sentinel_vE(float* out, int n, float val) {
  int t = blockIdx.x * 256 + threadIdx.x;
  if (t < n) out[t] = val;
}

// ---------------- prep + GRID thresholds (257-pt theta grid) + theta-band hist ----------------
#define GRIDB_ 129     // 129 blocks x 4 waves = 516 jobs >= 2*257
#define PREPN_ (M_ + B_*N_ + B_*H_)
#define PREPB_ ((PREPN_ + 255)/256)

__global__ __launch_bounds__(256) void prep_vE(
    const float* __restrict__ xxx, const float* __restrict__ pix,
    float4* __restrict__ r_pix, float4* __restrict__ r_los, float* __restrict__ gf,
    float* __restrict__ kthrG, float* __restrict__ cthrG, unsigned* __restrict__ cnt)
{
  const float PI = 3.14159265358979f;
  if ((int)blockIdx.x < GRIDB_) {
    int gid  = blockIdx.x*4 + (threadIdx.x >> 6);
    if (gid >= 514) return;
    int lane = threadIdx.x & 63;
    int tgt  = (gid >= 257) ? 1 : 0;
    int gp   = gid - tgt*257;
    float thp = (float)gp * (PI/256.f);
    float cp = cosf(thp), sp = fmaxf(sinf(thp), 1e-6f);
    float thq = ((float)lane + 0.5f) * (PI/64.f);
    float sq = sinf(thq), cq = cosf(thq);
    float rinv = 1.0f / (sq * sp);
    // E targets: sampler 128 of N, knn 48 of M (retry ladder covers tails)
    float At = tgt ? (2.f*PI*PI*128.f/(float)N_) : (2.f*PI*PI*48.f/(float)M_);
    float lo = 1e-3f, hi = 3.1414f;
    for (int it = 0; it < 12; ++it) {
      float al = 0.5f*(lo + hi);
      float ca = cosf(al);
      float arg = clamp1((ca - cq*cp) * rinv);
      float ax = fabsf(arg);
      float ac = sqrtf(fmaxf(0.f, 1.f - ax)) *
                 fmaf(ax, fmaf(ax, fmaf(ax, -0.0187293f, 0.0742610f), -0.2121144f), 1.5707288f);
      ac = (arg < 0.f) ? (PI - ac) : ac;
      float S = ac;
      #pragma unroll
      for (int off = 32; off; off >>= 1) S += __shfl_xor(S, off);
      float A = 2.f * S * (PI/64.f);
      if (A < At) lo = al; else hi = al;
    }
    if (lane == 0) {
      float chv = cosf(hi);
      if (tgt) cthrG[gp] = chv - 1e-5f;
      else     kthrG[gp] = 2.f*chv - 1.00002f;
    }
  } else {
    int tid = ((int)blockIdx.x - GRIDB_)*256 + threadIdx.x;
    if (tid < M_) {
      float th = pix[2*tid], ph = pix[2*tid+1];
      float st = sinf(th);
      float x = st*cosf(ph), y = st*sinf(ph), z = cosf(th);
      r_pix[tid] = make_float4(x, y, z, x*x + y*y + z*z);
      atomicAdd(&cnt[thbkt(th)], 1u);
    }
    int t2 = tid - M_;
    if (t2 >= 0 && t2 < B_*N_) {
      int b = t2 >> 12, n = t2 & (N_-1);
      const float* xb = xxx + b*3*N_;
      float th = xb[n], ph = xb[N_+n], ft = xb[2*N_+n];
      float st = sinf(th);
      r_los[t2] = make_float4(st*cosf(ph), st*sinf(ph), cosf(th), ft);
      atomicAdd(&cnt[256 + b*256 + thbkt(th)], 1u);
    }
    int t3 = tid - M_ - B_*N_;
    if (t3 >= 0 && t3 < B_*H_) gf[t3] = 0.0f;
  }
}

// ---------------- scan ----------------
__global__ __launch_bounds__(256) void scan_vE(
    const unsigned* __restrict__ cnt, int* __restrict__ pstart, int* __restrict__ lstart,
    unsigned* __restrict__ pcur, unsigned* __restrict__ lcur)
{
  __shared__ unsigned buf[256];
  const int t = threadIdx.x;
  for (int arr = 0; arr < 3; ++arr) {
    unsigned v = cnt[arr*256 + t];
    buf[t] = v;
    __syncthreads();
    for (int off = 1; off < 256; off <<= 1) {
      unsigned o = (t >= off) ? buf[t - off] : 0u;
      __syncthreads();
      buf[t] += o;
      __syncthreads();
    }
    unsigned incl = buf[t], excl = incl - v;
    if (arr == 0) {
      pstart[t] = (int)excl; if (t == 255) pstart[256] = (int)incl;
      pcur[t] = excl;
    } else {
      int b = arr - 1;
      lstart[b*257 + t] = (int)excl; if (t == 255) lstart[b*257 + 256] = (int)incl;
      lcur[b*256 + t] = excl;
    }
    __syncthreads();
  }
}

// ---------------- scatter ----------------
__global__ __launch_bounds__(256) void scatter_vE(
    const float* __restrict__ xxx, const float* __restrict__ pix,
    const float4* __restrict__ r_pix, const float4* __restrict__ r_los,
    unsigned* __restrict__ pcur, unsigned* __restrict__ lcur,
    float4* __restrict__ spix, int* __restrict__ sjdx,
    float4* __restrict__ slos, int* __restrict__ sldx)
{
  int tid = blockIdx.x * 256 + threadIdx.x;
  if (tid < M_) {
    int bkt = thbkt(pix[2*tid]);
    unsigned pos = atomicAdd(&pcur[bkt], 1u);
    spix[pos] = r_pix[tid];
    sjdx[pos] = tid;
  } else {
    int t2 = tid - M_;
    if (t2 < B_*N_) {
      int b = t2 >> 12, n = t2 & (N_-1);
      int bkt = thbkt(xxx[b*3*N_ + n]);
      unsigned pos = atomicAdd(&lcur[b*256 + bkt], 1u);
      slos[b*N_ + pos] = r_los[t2];
      sldx[b*N_ + pos] = n;
    }
  }
}

// ---------------- sampler vE: grid-threshold lookup + pass1 hist + merged pass2 ----------------
__global__ __launch_bounds__(512) void sampler_vE(
    const float* __restrict__ pix,
    const float4* __restrict__ spix, const int* __restrict__ sjdx,
    const float4* __restrict__ slos, const int* __restrict__ sldx,
    const int* __restrict__ lstart, const float4* __restrict__ r_los,
    const float* __restrict__ cthrG,
    const float* __restrict__ aw1, const float* __restrict__ ab1,
    const float* __restrict__ aw2, const float* __restrict__ ab2,
    float* __restrict__ pooled)
{
  __shared__ unsigned long long selKey[16][K_];     // 8 KB
  __shared__ unsigned long long bndK[16][BCAP2];    // 6 KB
  __shared__ unsigned hist[16][64];                 // 4 KB

  const int tid = threadIdx.x, wv = tid >> 6, lane = tid & 63;
  const int b  = blockIdx.y;
  const int srow0 = blockIdx.x*16 + wv*2, srow1 = srow0 + 1;
  const int r0 = wv*2, r1 = r0 + 1;
  const int m0 = sjdx[srow0], m1 = sjdx[srow1];
  const float4 p0 = spix[srow0], p1 = spix[srow1];
  const float thp0 = pix[2*m0], thp1 = pix[2*m1];
  const int g0 = thbkt(thp0), g1 = thbkt(thp1);
  const float th0 = fminf(cthrG[g0], cthrG[g0+1]);
  const float th1 = fminf(cthrG[g1], cthrG[g1+1]);
  const float inv0 = 63.999f / (1.000001f - th0);
  const float inv1 = 63.999f / (1.000001f - th1);
  const float4* sl = slos + b * N_;
  const int* sx = sldx + b * N_;
  const float4* rl = r_los + b * N_;
  const int* ls = lstart + b * 257;
  const unsigned long long ltm = (1ull << lane) - 1ull;

  hist[r0][lane] = 0u; hist[r1][lane] = 0u;

  // union window bounds
  int jlo, jhi;
  {
    float al0 = acosf(clamp1(th0)), al1 = acosf(clamp1(th1));
    int blo = thbkt(fminf(thp0 - al0, thp1 - al1) - MG_);
    int bhi = thbkt(fmaxf(thp0 + al0, thp1 + al1) + MG_);
    jlo = ls[blo]; jhi = ls[bhi + 1];
  }

  // pass 1: count + histogram (no candidate store)
  unsigned cnt0 = 0, cnt1 = 0;
  for (int base = jlo; base < jhi; base += 64) {
    int pos = base + lane;
    bool act = pos < jhi;
    float c0 = -2.f, c1 = -2.f;
    if (act) {
      float4 v = sl[pos];
      c0 = clamp1(v.x*p0.x + v.y*p0.y + v.z*p0.z);
      c1 = clamp1(v.x*p1.x + v.y*p1.y + v.z*p1.z);
    }
    bool pr0 = c0 > th0, pr1 = c1 > th1;
    if (pr0) atomicAdd(&hist[r0][(int)((c0 - th0) * inv0)], 1u);
    if (pr1) atomicAdd(&hist[r1][(int)((c1 - th1) * inv1)], 1u);
    cnt0 += (unsigned)__popcll(__ballot(pr0));
    cnt1 += (unsigned)__popcll(__ballot(pr1));
  }

  // fast-path select params for rows with enough candidates
  bool ok[2] = { cnt0 >= K_, cnt1 >= K_ };
  int tsel[2]; unsigned chi_[2], need_[2];
  for (int rr = 0; rr < 2; ++rr) {
    tsel[rr] = 64; chi_[rr] = 0; need_[rr] = 0;
    if (ok[rr]) {
      const int r = (rr == 0) ? r0 : r1;
      unsigned g = hist[r][lane], s = g;
      #pragma unroll
      for (int off = 1; off < 64; off <<= 1) {
        unsigned t2 = (unsigned)__shfl_down((int)s, off);
        s += (lane + off < 64) ? t2 : 0u;
      }
      unsigned snext = s - g;
      unsigned packed = (s >= K_ && snext < K_) ? (((unsigned)(lane+1) << 16) | snext) : 0u;
      #pragma unroll
      for (int off = 32; off; off >>= 1) {
        unsigned o = (unsigned)__shfl_xor((int)packed, off);
        packed = packed > o ? packed : o;
      }
      tsel[rr] = (int)(packed >> 16) - 1;
      chi_[rr] = packed & 0xFFFFu;
      need_[rr] = K_ - chi_[rr];
    }
  }

  // merged pass 2: one scan collecting winners + boundary for both ok rows
  bool done[2] = { false, false };
  if (ok[0] || ok[1]) {
    unsigned hiC0 = 0, bdC0 = 0, hiC1 = 0, bdC1 = 0;
    for (int base = jlo; base < jhi; base += 64) {
      int pos = base + lane;
      bool act = pos < jhi;
      float c0 = -2.f, c1 = -2.f; int n = 0;
      if (act) {
        float4 v = sl[pos]; n = sx[pos];
        c0 = clamp1(v.x*p0.x + v.y*p0.y + v.z*p0.z);
        c1 = clamp1(v.x*p1.x + v.y*p1.y + v.z*p1.z);
      }
      if (ok[0]) {
        int bin = (act && c0 > th0) ? (int)((c0 - th0) * inv0) : -1;
        bool pHi = bin > tsel[0], pBd = bin == tsel[0];
        unsigned long long mH = __ballot(pHi);
        unsigned offH = (unsigned)__popcll(mH & ltm);
        if (pHi && hiC0 + offH < K_) selKey[r0][hiC0 + offH] = spack(c0, n);
        hiC0 += (unsigned)__popcll(mH);
        unsigned long long mB = __ballot(pBd);
        unsigned offB = (unsigned)__popcll(mB & ltm);
        if (pBd && bdC0 + offB < BCAP2) bndK[r0][bdC0 + offB] = spack(c0, n);
        bdC0 += (unsigned)__popcll(mB);
      }
      if (ok[1]) {
        int bin = (act && c1 > th1) ? (int)((c1 - th1) * inv1) : -1;
        bool pHi = bin > tsel[1], pBd = bin == tsel[1];
        unsigned long long mH = __ballot(pHi);
        unsigned offH = (unsigned)__popcll(mH & ltm);
        if (pHi && hiC1 + offH < K_) selKey[r1][hiC1 + offH] = spack(c1, n);
        hiC1 += (unsigned)__popcll(mH);
        unsigned long long mB = __ballot(pBd);
        unsigned offB = (unsigned)__popcll(mB & ltm);
        if (pBd && bdC1 + offB < BCAP2) bndK[r1][bdC1 + offB] = spack(c1, n);
        bdC1 += (unsigned)__popcll(mB);
      }
    }
    for (int rr = 0; rr < 2; ++rr) {
      if (!ok[rr]) continue;
      unsigned bdC = (rr == 0) ? bdC0 : bdC1;
      const int r = (rr == 0) ? r0 : r1;
      if (bdC <= (unsigned)BCAP2) {
        if (lane < (int)bdC) {
          unsigned long long ki = bndK[r][lane];
          int rank = 0;
          for (int j = 0; j < (int)bdC; ++j) rank += (bndK[r][j] > ki) ? 1 : 0;
          if ((unsigned)rank < need_[rr]) selKey[r][chi_[rr] + rank] = ki;
        }
        done[rr] = true;
      }
    }
  }

  for (int rr = 0; rr < 2; ++rr) {
    const int r = (rr == 0) ? r0 : r1;
    const int m = (rr == 0) ? m0 : m1;
    const float4 p = (rr == 0) ? p0 : p1;
    const float thp = (rr == 0) ? thp0 : thp1;

    if (!done[rr]) {
      // slow path (rare): retry ladder + per-row hist select, else ultimate
      float th = (rr == 0) ? th0 : th1;
      float inv = (rr == 0) ? inv0 : inv1;
      unsigned cn = (rr == 0) ? cnt0 : cnt1;
      int wlo = jlo, whi = jhi;

      int tries = 0;
      while (cn < K_ && tries < 3) {
        th = 1.f - 1.6f*(1.f - th); ++tries;
        inv = 63.999f / (1.000001f - th);
        float al = acosf(clamp1(th));
        int blo = thbkt(thp - al - MG_), bhi = thbkt(thp + al + MG_);
        wlo = ls[blo]; whi = ls[bhi + 1];
        hist[r][lane] = 0u;
        cn = 0;
        for (int base = wlo; base < whi; base += 64) {
          int pos = base + lane;
          bool act = pos < whi;
          float c = -2.f;
          if (act) {
            float4 v = sl[pos];
            c = clamp1(v.x*p.x + v.y*p.y + v.z*p.z);
          }
          bool pr = c > th;
          if (pr) atomicAdd(&hist[r][(int)((c - th) * inv)], 1u);
          cn += (unsigned)__popcll(__ballot(pr));
        }
      }

      bool fin = false;
      if (cn >= K_) {
        unsigned g = hist[r][lane], s = g;
        #pragma unroll
        for (int off = 1; off < 64; off <<= 1) {
          unsigned t2 = (unsigned)__shfl_down((int)s, off);
          s += (lane + off < 64) ? t2 : 0u;
        }
        unsigned snext = s - g;
        unsigned packed = (s >= K_ && snext < K_) ? (((unsigned)(lane+1) << 16) | snext) : 0u;
        #pragma unroll
        for (int off = 32; off; off >>= 1) {
          unsigned o = (unsigned)__shfl_xor((int)packed, off);
          packed = packed > o ? packed : o;
        }
        const int t = (int)(packed >> 16) - 1;
        const unsigned chi = packed & 0xFFFFu;
        const unsigned need = K_ - chi;

        unsigned hiC = 0, bdC = 0;
        for (int base = wlo; base < whi; base += 64) {
          int pos = base + lane;
          bool act = pos < whi;
          float c = -2.f; int n = 0;
          if (act) {
            float4 v = sl[pos]; n = sx[pos];
            c = clamp1(v.x*p.x + v.y*p.y + v.z*p.z);
          }
          int bin = (act && c > th) ? (int)((c - th) * inv) : -1;
          bool pHi = bin > t;
          bool pBd = bin == t;
          unsigned long long mH = __ballot(pHi);
          unsigned offH = (unsigned)__popcll(mH & ltm);
          if (pHi && hiC + offH < K_) selKey[r][hiC + offH] = spack(c, n);
          hiC += (unsigned)__popcll(mH);
          unsigned long long mB = __ballot(pBd);
          unsigned offB = (unsigned)__popcll(mB & ltm);
          if (pBd && bdC + offB < BCAP2) bndK[r][bdC + offB] = spack(c, n);
          bdC += (unsigned)__popcll(mB);
        }
        if (bdC <= (unsigned)BCAP2) {
          if (lane < (int)bdC) {
            unsigned long long ki = bndK[r][lane];
            int rank = 0;
            for (int j = 0; j < (int)bdC; ++j) rank += (bndK[r][j] > ki) ? 1 : 0;
            if ((unsigned)rank < need) selKey[r][chi + rank] = ki;
          }
          fin = true;
        }
      }

      if (!fin) {
        unsigned long long prev = ~0ull;
        for (int rd = 0; rd < K_; ++rd) {
          unsigned long long best = 0ull;
          for (int i = 0; i < 64; ++i) {
            int n = lane + 64*i;
            float4 v = rl[n];
            float c = clamp1(v.x*p.x + v.y*p.y + v.z*p.z);
            unsigned long long k = spack(c, n);
            if (k < prev && k > best) best = k;
          }
          #pragma unroll
          for (int off = 1; off < 64; off <<= 1) {
            unsigned long long o = shflxor64(best, off);
            best = o > best ? o : best;
          }
          if (lane == 0) selKey[r][rd] = best;
          prev = best;
        }
      }
    }

    // attention MLP + softmax + weighted pool
    {
      unsigned long long key = selKey[r][lane];
      int n = 4095 - (int)(key & 0xFFFull);
      float c = key2f((unsigned)(key >> 12));
      float xg = rl[n].w;
      float d  = acosf(clamp1(c));
      float acc = ab2[0];
      for (int s2 = 0; s2 < SH_; ++s2)
        acc += fmaxf(xg*aw1[s2] + d*aw1[SH_+s2] + ab1[s2], 0.f) * aw2[s2];
      float mx = acc;
      #pragma unroll
      for (int off = 32; off; off >>= 1) mx = fmaxf(mx, __shfl_xor(mx, off));
      float e = expf(acc - mx);
      float se = e, sxe = e * xg;
      #pragma unroll
      for (int off = 32; off; off >>= 1) { se += __shfl_xor(se, off); sxe += __shfl_xor(sxe, off); }
      if (lane == 0) pooled[b*M_ + m] = sxe / se;
    }
  }
}

// ---------------- knn vE (grid-threshold lookup; KCAP=128, 16 KB LDS) ----------------
__global__ __launch_bounds__(512) void knn_vE(
    const float* __restrict__ pix,
    const float4* __restrict__ spix, const int* __restrict__ sjdx,
    const int* __restrict__ pstart, const float4* __restrict__ r_pix,
    const float* __restrict__ kthrG, int* __restrict__ nbr)
{
  __shared__ unsigned long long cKey[16][KCAP];

  const int tid = threadIdx.x, wv = tid >> 6, lane = tid & 63;
  const int lr0 = wv*2;
  const int srow0 = blockIdx.x*16 + lr0, srow1 = srow0 + 1;
  const int i0 = sjdx[srow0], i1 = sjdx[srow1];
  const float4 p0 = spix[srow0], p1 = spix[srow1];
  const float thp0 = pix[2*i0], thp1 = pix[2*i1];
  const int g0 = thbkt(thp0), g1 = thbkt(thp1);
  const float t0 = fminf(kthrG[g0], kthrG[g0+1]);
  const float t1 = fminf(kthrG[g1], kthrG[g1+1]);
  const unsigned long long ltm = (1ull << lane) - 1ull;

  unsigned cnt0 = 0, cnt1 = 0;
  {
    float al0 = acosf(clamp1((t0 + 1.00002f)*0.5f));
    float al1 = acosf(clamp1((t1 + 1.00002f)*0.5f));
    int blo = thbkt(fminf(thp0 - al0, thp1 - al1) - MG_);
    int bhi = thbkt(fmaxf(thp0 + al0, thp1 + al1) + MG_);
    int jlo = pstart[blo], jhi = pstart[bhi + 1];
    for (int base = jlo; base < jhi; base += 64) {
      int pos = base + lane;
      bool act = pos < jhi;
      float s0 = -1e30f, s1 = -1e30f; int j = -1;
      if (act) {
        float4 v = spix[pos]; j = sjdx[pos];
        s0 = 2.f*(p0.x*v.x + p0.y*v.y + p0.z*v.z) - v.w;
        s1 = 2.f*(p1.x*v.x + p1.y*v.y + p1.z*v.z) - v.w;
      }
      bool pr0 = act && (j != i0) && (s0 > t0);
      bool pr1 = act && (j != i1) && (s1 > t1);
      unsigned long long mk0 = __ballot(pr0);
      if (mk0) {
        unsigned off = (unsigned)__popcll(mk0 & ltm);
        if (pr0 && cnt0 + off < KCAP) cKey[lr0][cnt0 + off] = kpack(s0, j);
        cnt0 += (unsigned)__popcll(mk0);
      }
      unsigned long long mk1 = __ballot(pr1);
      if (mk1) {
        unsigned off = (unsigned)__popcll(mk1 & ltm);
        if (pr1 && cnt1 + off < KCAP) cKey[lr0+1][cnt1 + off] = kpack(s1, j);
        cnt1 += (unsigned)__popcll(mk1);
      }
    }
  }

  for (int rr = 0; rr < 2; ++rr) {
    const int lr = lr0 + rr;
    const int i  = (rr == 0) ? i0 : i1;
    const float4 pi = (rr == 0) ? p0 : p1;
    const float thp = (rr == 0) ? thp0 : thp1;
    float th = (rr == 0) ? t0 : t1;
    unsigned cn = (rr == 0) ? cnt0 : cnt1;

    int tries = 0;
    while (cn < (unsigned)GK_ && tries < 3) {
      th = 1.6f*th - 0.6f; ++tries;
      float al = acosf(clamp1((th + 1.00002f)*0.5f));
      int blo = thbkt(thp - al - MG_), bhi = thbkt(thp + al + MG_);
      int jlo = pstart[blo], jhi = pstart[bhi + 1];
      cn = 0;
      for (int base = jlo; base < jhi; base += 64) {
        int pos = base + lane;
        bool act = pos < jhi;
        float s = -1e30f; int j = -1;
        if (act) {
          float4 v = spix[pos]; j = sjdx[pos];
          s = 2.f*(pi.x*v.x + pi.y*v.y + pi.z*v.z) - v.w;
        }
        bool pr = act && (j != i) && (s > th);
        unsigned long long mk = __ballot(pr);
        if (mk) {
          unsigned off = (unsigned)__popcll(mk & ltm);
          if (pr && cn + off < KCAP) cKey[lr][cn + off] = kpack(s, j);
          cn += (unsigned)__popcll(mk);
        }
      }
    }

    if (cn >= (unsigned)GK_ && cn <= (unsigned)KCAP) {
      unsigned long long pk[2];
      #pragma unroll
      for (int t2 = 0; t2 < 2; ++t2) {
        int idx = lane + 64*t2;
        pk[t2] = (idx < (int)cn) ? cKey[lr][idx] : 0ull;
      }
      for (int round = 0; round < GK_; ++round) {
        unsigned long long loc = pk[0]; int lt = 0;
        if (pk[1] > loc) { loc = pk[1]; lt = 1; }
        unsigned long long best = loc;
        #pragma unroll
        for (int off = 1; off < 64; off <<= 1) {
          unsigned long long o = shflxor64(best, off);
          best = o > best ? o : best;
        }
        if (loc == best) pk[lt] = 0ull;
        if (lane == round) nbr[i*GK_ + round] = 16383 - (int)(best & 16383ull);
      }
    } else {
      unsigned long long prev = ~0ull;
      for (int rd = 0; rd < GK_; ++rd) {
        unsigned long long best = 0ull;
        for (int j = lane; j < M_; j += 64) {
          float4 v = r_pix[j];
          float s = 2.f*(pi.x*v.x + pi.y*v.y + pi.z*v.z) - v.w;
          if (j != i) {
            unsigned long long k = kpack(s, j);
            if (k < prev && k > best) best = k;
          }
        }
        #pragma unroll
        for (int off = 1; off < 64; off <<= 1) {
          unsigned long long o = shflxor64(best, off);
          best = o > best ? o : best;
        }
        if (lane == rd) nbr[i*GK_ + rd] = 16383 - (int)(best & 16383ull);
        prev = best;
      }
    }
  }
}

// ---------------- GNN layer 1 fused with proj (readlane matmul) ----------------
__global__ __launch_bounds__(256) void gnn1f_vE(
    const float* __restrict__ pooled, float* __restrict__ hout, const int* __restrict__ nbr,
    const float* __restrict__ pw, const float* __restrict__ pb,
    const float* __restrict__ relw, const float* __restrict__ relb,
    const float* __restrict__ rootw)
{
  __shared__ float wrel[H_*H_], wroot[H_*H_];
  const int tid = threadIdx.x;
  #pragma unroll
  for (int q = 0; q < 16; ++q) {
    int idx = tid + 256*q;
    wrel[idx]  = relw[idx];
    wroot[idx] = rootw[idx];
  }
  __syncthreads();

  const int lane = tid & 63;
  const int wave = tid >> 6;
  const int b = blockIdx.y;
  const int m0 = blockIdx.x * 16 + wave * 4;
  const float* pldb = pooled + (size_t)b * M_;
  const float pwl = pw[lane], pbl = pb[lane], rbl = relb[lane];

  float h[4], agg[4], acc[4];
  #pragma unroll
  for (int t = 0; t < 4; ++t) {
    int m = m0 + t;
    float ps = pldb[m];
    h[t] = fmaxf(ps*pwl + pbl, 0.f);
    float a = 0.f;
    #pragma unroll
    for (int k = 0; k < GK_; ++k) {
      int nb = nbr[m*GK_ + k];
      nb = nb < 0 ? 0 : (nb >= M_ ? M_-1 : nb);
      float pn = pldb[nb];
      a += fmaxf(pn*pwl + pbl, 0.f);
    }
    agg[t] = a;
    acc[t] = rbl;
  }
  #pragma unroll
  for (int c = 0; c < H_; ++c) {
    float wr = wrel[c*H_ + lane], wo = wroot[c*H_ + lane];
    #pragma unroll
    for (int t = 0; t < 4; ++t)
      acc[t] += rdlane(agg[t], c) * wr + rdlane(h[t], c) * wo;
  }
  #pragma unroll
  for (int t = 0; t < 4; ++t)
    hout[((size_t)b*M_ + m0 + t)*H_ + lane] = fmaxf(acc[t], 0.f);
}

// ---------------- GNN layer (generic, readlane matmul) ----------------
__global__ __launch_bounds__(256) void gnn_vE(
    const float* __restrict__ hin, float* __restrict__ hout, const int* __restrict__ nbr,
    const float* __restrict__ relw, const float* __restrict__ relb,
    const float* __restrict__ rootw)
{
  __shared__ float wrel[H_*H_], wroot[H_*H_];
  const int tid = threadIdx.x;
  #pragma unroll
  for (int q = 0; q < 16; ++q) {
    int idx = tid + 256*q;
    wrel[idx]  = relw[idx];
    wroot[idx] = rootw[idx];
  }
  __syncthreads();

  const int lane = tid & 63;
  const int wave = tid >> 6;
  const int b = blockIdx.y;
  const int m0 = blockIdx.x * 16 + wave * 4;
  const float* hb = hin + (size_t)b * M_ * H_;
  const float rbl = relb[lane];

  float h[4], agg[4], acc[4];
  #pragma unroll
  for (int t = 0; t < 4; ++t) {
    int m = m0 + t;
    h[t] = hb[m*H_ + lane];
    float a = 0.f;
    #pragma unroll
    for (int k = 0; k < GK_; ++k) {
      int nb = nbr[m*GK_ + k];
      nb = nb < 0 ? 0 : (nb >= M_ ? M_-1 : nb);
      a += hb[nb*H_ + lane];
    }
    agg[t] = a;
    acc[t] = rbl;
  }
  #pragma unroll
  for (int c = 0; c < H_; ++c) {
    float wr = wrel[c*H_ + lane], wo = wroot[c*H_ + lane];
    #pragma unroll
    for (int t = 0; t < 4; ++t)
      acc[t] += rdlane(agg[t], c) * wr + rdlane(h[t], c) * wo;
  }
  #pragma unroll
  for (int t = 0; t < 4; ++t)
    hout[((size_t)b*M_ + m0 + t)*H_ + lane] = fmaxf(acc[t], 0.f);
}

// ---------------- GNN layer 3 + fused global-mean reduce ----------------
__global__ __launch_bounds__(256) void gnn3r_vE(
    const float* __restrict__ hin, float* __restrict__ gf, const int* __restrict__ nbr,
    const float* __restrict__ relw, const float* __restrict__ relb,
    const float* __restrict__ rootw)
{
  __shared__ float wrel[H_*H_], wroot[H_*H_];
  __shared__ float gacc[H_];
  const int tid = threadIdx.x;
  #pragma unroll
  for (int q = 0; q < 16; ++q) {
    int idx = tid + 256*q;
    wrel[idx]  = relw[idx];
    wroot[idx] = rootw[idx];
  }
  if (tid < H_) gacc[tid] = 0.f;
  __syncthreads();

  const int lane = tid & 63;
  const int wave = tid >> 6;
  const int b = blockIdx.y;
  const int m0 = blockIdx.x * 16 + wave * 4;
  const float* hb = hin + (size_t)b * M_ * H_;
  const float rbl = relb[lane];

  float h[4], agg[4], acc[4];
  #pragma unroll
  for (int t = 0; t < 4; ++t) {
    int m = m0 + t;
    h[t] = hb[m*H_ + lane];
    float a = 0.f;
    #pragma unroll
    for (int k = 0; k < GK_; ++k) {
      int nb = nbr[m*GK_ + k];
      nb = nb < 0 ? 0 : (nb >= M_ ? M_-1 : nb);
      a += hb[nb*H_ + lane];
    }
    agg[t] = a;
    acc[t] = rbl;
  }
  #pragma unroll
  for (int c = 0; c < H_; ++c) {
    float wr = wrel[c*H_ + lane], wo = wroot[c*H_ + lane];
    #pragma unroll
    for (int t = 0; t < 4; ++t)
      acc[t] += rdlane(agg[t], c) * wr + rdlane(h[t], c) * wo;
  }
  float ps = fmaxf(acc[0], 0.f) + fmaxf(acc[1], 0.f) + fmaxf(acc[2], 0.f) + fmaxf(acc[3], 0.f);
  atomicAdd(&gacc[lane], ps);
  __syncthreads();
  if (tid < H_) atomicAdd(&gf[b*H_ + tid], gacc[tid]);
}

// ---------------- head ----------------
__global__ __launch_bounds__(256) void head_vE(
    const float* __restrict__ gf, const float* __restrict__ w1,
    const float* __restrict__ b1, const float* __restrict__ w2,
    const float* __restrict__ b2, float* __restrict__ out)
{
  __shared__ float gfm[B_][H_], hid[B_][H_];
  const int tid = threadIdx.x;
  if (tid < B_*H_) gfm[tid >> 6][tid & 63] = gf[tid] * (1.f / (float)M_);
  __syncthreads();
  if (tid < B_*H_) {
    int b = tid >> 6, j = tid & 63;
    float acc = b1[j];
    for (int c = 0; c < H_; ++c) acc += gfm[b][c] * w1[c*H_ + j];
    hid[b][j] = fmaxf(acc, 0.f);
  }
  __syncthreads();
  for (int t = tid; t < B_*NC_; t += 256) {
    int b = t / NC_, o = t - b*NC_;
    float acc = b2[o];
    for (int j = 0; j < H_; ++j) acc += hid[b][j] * w2[j*NC_ + o];
    out[t] = acc;
  }
}

extern "C" void kernel_launch(void* const* d_in, const int* in_sizes, int n_in,
                              void* d_out, int out_size, void* d_ws, size_t ws_size,
                              hipStream_t stream)
{
  float* out = (float*)d_out;

  const size_t need = (size_t)M_*16 + (size_t)B_*N_*16 + (size_t)B_*M_*4
                    + (size_t)M_*GK_*4 + 2*(size_t)B_*M_*H_*4 + (size_t)B_*H_*4;
  bool ok_ws = ws_size >= need;
  bool ok_in = (n_in == 15) && (out_size == B_*NC_)
            && in_sizes[0] == B_*3*N_ && in_sizes[1] == M_*2
            && in_sizes[2] == 2*SH_ && in_sizes[5] == 1
            && in_sizes[8] == 3*H_*H_ && in_sizes[13] == H_*NC_;
  if (!ok_ws || !ok_in) {
    sentinel_vE<<<(out_size + 255)/256, 256, 0, stream>>>(out, out_size, ok_in ? 42.f : 43.f);
    return;
  }

  const float* xxx    = (const float*)d_in[0];
  const float* pix    = (const float*)d_in[1];
  const float* att_w1 = (const float*)d_in[2];
  const float* att_b1 = (const float*)d_in[3];
  const float* att_w2 = (const float*)d_in[4];
  const float* att_b2 = (const float*)d_in[5];
  const float* proj_w = (const float*)d_in[6];
  const float* proj_b = (const float*)d_in[7];
  const float* rel_w  = (const float*)d_in[8];
  const float* rel_b  = (const float*)d_in[9];
  const float* root_w = (const float*)d_in[10];
  const float* out_w1 = (const float*)d_in[11];
  const float* out_b1 = (const float*)d_in[12];
  const float* out_w2 = (const float*)d_in[13];
  const float* out_b2 = (const float*)d_in[14];

  char* w = (char*)d_ws;
  float4* r_pix = (float4*)w;  w += (size_t)M_ * 16;
  float4* r_los = (float4*)w;  w += (size_t)B_ * N_ * 16;
  float*  pooled = (float*)w;  w += (size_t)B_ * M_ * 4;
  int*    nbr = (int*)w;       w += (size_t)M_ * GK_ * 4;
  float*  h0 = (float*)w;      w += (size_t)B_ * M_ * H_ * 4;
  float*  h1 = (float*)w;      w += (size_t)B_ * M_ * H_ * 4;
  float*  gf = (float*)w;      w += (size_t)B_ * H_ * 4;

  // sort/threshold scratch aliases h0 (dead until gnn layer 2 writes it)
  float*  kthrG = h0;                                  // 257 grid thresholds (knn)
  float*  cthrG = h0 + 512;                            // 257 grid thresholds (sampler)
  float4* spix = (float4*)(h0 + 2*M_);                 // M float4
  int*    sjdx = (int*)(h0 + 6*M_);                    // M
  float4* slos = (float4*)(h0 + 7*M_);                 // B*N float4
  int*    sldx = (int*)(h0 + 7*M_ + 4*B_*N_);          // B*N
  unsigned* cnt = (unsigned*)(h0 + 7*M_ + 5*B_*N_);    // 768
  int*    pstart = (int*)(cnt + 768);                  // 257
  int*    lstart = pstart + 257;                       // 2*257
  unsigned* pcur = (unsigned*)(lstart + 514);          // 256
  unsigned* lcur = pcur + 256;                         // 512

  hipMemsetAsync(cnt, 0, 768*sizeof(unsigned), stream);
  prep_vE<<<GRIDB_ + PREPB_, 256, 0, stream>>>(xxx, pix, r_pix, r_los, gf, kthrG, cthrG, cnt);
  scan_vE<<<1, 256, 0, stream>>>(cnt, pstart, lstart, pcur, lcur);
  scatter_vE<<<(M_ + B_*N_ + 255)/256, 256, 0, stream>>>(xxx, pix, r_pix, r_los, pcur, lcur,
                                                         spix, sjdx, slos, sldx);
  sampler_vE<<<dim3(M_/16, B_), 512, 0, stream>>>(pix, spix, sjdx, slos, sldx, lstart, r_los,
                                                  cthrG, att_w1, att_b1, att_w2, att_b2, pooled);
  knn_vE<<<M_/16, 512, 0, stream>>>(pix, spix, sjdx, pstart, r_pix, kthrG, nbr);
  gnn1f_vE<<<dim3(M_/16, B_), 256, 0, stream>>>(pooled, h1, nbr, proj_w, proj_b,
                                                rel_w + 0*H_*H_, rel_b + 0*H_, root_w + 0*H_*H_);
  gnn_vE<<<dim3(M_/16, B_), 256, 0, stream>>>(h1, h0, nbr, rel_w + 1*H_*H_, rel_b + 1*H_, root_w + 1*H_*H_);
  gnn3r_vE<<<dim3(M_/16, B_), 256, 0, stream>>>(h0, gf, nbr, rel_w + 2*H_*H_, rel_b + 2*H_, root_w + 2*H_*H_);
  head_vE<<<1, 256, 0, stream>>>(gf, out_w1, out_b1, out_w2, out_b2, out);
}